// Round 11
// baseline (660.913 us; speedup 1.0000x reference)
//
#include <hip/hip_runtime.h>

// ---------------------------------------------------------------------------
// Enhanced_transformer  B=8, N=4096, P=1024, P4=256  (all fp32 in/out)
//
// Logit path (Qt, energy, G, a2): fp16-SPLIT MFMA (hi+lo, 3 MFMA/pair).
// Value path: plain f16 MFMA; t_out folded: x1 = NT(h, W_effT)+b_eff+x.
// R11: (1) Qt grid-swap (SWAP template) so both M-tiles of an h-panel land
//      on one XCD -> h fetched once (was 2x = 268 MB);
//      (2) LN2 fused into m1 (gemm_m: reg-staged A with on-the-fly
//      normalize; stats16 precomputes mu/rsig) -> ln16 + h2 deleted.
// ---------------------------------------------------------------------------

typedef __attribute__((ext_vector_type(4))) float f32x4;
typedef __attribute__((ext_vector_type(8))) _Float16 h16x8;
typedef __attribute__((ext_vector_type(8))) unsigned short u16x8;
typedef __attribute__((ext_vector_type(4))) unsigned short u16x4;

__device__ __forceinline__ unsigned short f2h(float f) {
  _Float16 h = (_Float16)f;
  return __builtin_bit_cast(unsigned short, h);
}
__device__ __forceinline__ float h2f(unsigned short u) {
  return (float)__builtin_bit_cast(_Float16, u);
}
// returns hi in bits[15:0], lo in bits[31:16]
__device__ __forceinline__ unsigned split16(float f) {
  _Float16 h = (_Float16)f;
  _Float16 l = (_Float16)(f - (float)h);
  return (unsigned)__builtin_bit_cast(unsigned short, h) |
         ((unsigned)__builtin_bit_cast(unsigned short, l) << 16);
}
__device__ __forceinline__ float gelu_f(float x) {
  return 0.5f * x * (1.0f + erff(x * 0.70710678118654752f));
}
__device__ __forceinline__ void gload16(const void* g, void* l) {
  __builtin_amdgcn_global_load_lds(
      (const __attribute__((address_space(1))) unsigned int*)g,
      (__attribute__((address_space(3))) unsigned int*)l, 16, 0, 0);
}
#define FENCE() asm volatile("" ::: "memory")

// XCD chunk-swizzle, ROW-major flatten (bx fastest): per-XCD working set =
// few A-panels + whole B panel (L2-resident). [R8 measured: 164 MB fetch]
__device__ __forceinline__ void xcd_swz(int& bx, int& by, int gx, int gy) {
  const int nwg = gx * gy;
  if ((nwg & 7) == 0 && nwg >= 16) {
    const int flat = bx + gx * by;
    const int chunk = nwg >> 3;
    const int nf = (flat & 7) * chunk + (flat >> 3);
    bx = nf % gx;
    by = nf / gx;
  }
}

// ---------------- LayerNorm (f32 in): hi/lo f16 planes + raw xh f16 --------
__global__ __launch_bounds__(256)
void ln_kernel(const float* __restrict__ x, const float* __restrict__ g,
               const float* __restrict__ b, unsigned short* __restrict__ hi,
               unsigned short* __restrict__ lo, unsigned short* __restrict__ xh) {
  __shared__ float red[16];
  const size_t base = (size_t)blockIdx.x * 1024;
  const int t = threadIdx.x;
  f32x4 v = *(const f32x4*)&x[base + t * 4];
  float s = v[0] + v[1] + v[2] + v[3];
  float q = v[0] * v[0] + v[1] * v[1] + v[2] * v[2] + v[3] * v[3];
#pragma unroll
  for (int o = 32; o > 0; o >>= 1) { s += __shfl_down(s, o); q += __shfl_down(q, o); }
  const int w = t >> 6;
  if ((t & 63) == 0) { red[w] = s; red[8 + w] = q; }
  __syncthreads();
  s = (red[0] + red[1]) + (red[2] + red[3]);
  q = (red[8] + red[9]) + (red[10] + red[11]);
  const float mu = s * (1.0f / 1024.0f);
  const float var = q * (1.0f / 1024.0f) - mu * mu;
  const float is = rsqrtf(var + 1e-5f);
  f32x4 gg = *(const f32x4*)&g[t * 4];
  f32x4 bb = *(const f32x4*)&b[t * 4];
  u16x4 oh, ol, ox;
#pragma unroll
  for (int j = 0; j < 4; j++) {
    float y = (v[j] - mu) * is * gg[j] + bb[j];
    unsigned p = split16(y);
    oh[j] = (unsigned short)(p & 0xffffu);
    ol[j] = (unsigned short)(p >> 16);
    ox[j] = f2h(v[j]);
  }
  *(u16x4*)&hi[base + t * 4] = oh;
  if (lo) *(u16x4*)&lo[base + t * 4] = ol;
  if (xh) *(u16x4*)&xh[base + t * 4] = ox;
}

// ---------------- row stats (f16 in): muis[row] = {mu, rsig} ---------------
__global__ __launch_bounds__(256)
void stats16_kernel(const unsigned short* __restrict__ x16, float* __restrict__ muis) {
  __shared__ float red[16];
  const size_t base = (size_t)blockIdx.x * 1024;
  const int t = threadIdx.x;
  u16x4 raw = *(const u16x4*)&x16[base + t * 4];
  float v[4];
#pragma unroll
  for (int j = 0; j < 4; j++) v[j] = h2f(raw[j]);
  float s = v[0] + v[1] + v[2] + v[3];
  float q = v[0] * v[0] + v[1] * v[1] + v[2] * v[2] + v[3] * v[3];
#pragma unroll
  for (int o = 32; o > 0; o >>= 1) { s += __shfl_down(s, o); q += __shfl_down(q, o); }
  const int w = t >> 6;
  if ((t & 63) == 0) { red[w] = s; red[8 + w] = q; }
  __syncthreads();
  if (t == 0) {
    s = (red[0] + red[1]) + (red[2] + red[3]);
    q = (red[8] + red[9]) + (red[10] + red[11]);
    const float mu = s * (1.0f / 1024.0f);
    const float var = q * (1.0f / 1024.0f) - mu * mu;
    muis[blockIdx.x * 2] = mu;
    muis[blockIdx.x * 2 + 1] = rsqrtf(var + 1e-5f);
  }
}

// ---------------- fp32 -> f16 (hi + optional lo) ---------------------------
__global__ __launch_bounds__(256)
void cvt_kernel(const float* __restrict__ in, unsigned short* __restrict__ hi,
                unsigned short* __restrict__ lo, int n4) {
  int i = blockIdx.x * 256 + threadIdx.x;
  if (i < n4) {
    f32x4 v = *(const f32x4*)&in[(size_t)i * 4];
    u16x4 oh, ol;
#pragma unroll
    for (int j = 0; j < 4; j++) {
      unsigned p = split16(v[j]);
      oh[j] = (unsigned short)(p & 0xffffu);
      ol[j] = (unsigned short)(p >> 16);
    }
    *(u16x4*)&hi[(size_t)i * 4] = oh;
    if (lo) *(u16x4*)&lo[(size_t)i * 4] = ol;
  }
}

// ---------------- v_w (f32, PxP) -> transposed f16 wv_t[j][p] --------------
__global__ __launch_bounds__(256)
void vwt_kernel(const float* __restrict__ vw, unsigned short* __restrict__ wvt) {
  __shared__ float T[64][65];
  const int bx = blockIdx.x, by = blockIdx.y;   // j-tile, p-tile
  const int t = threadIdx.x;
  const int lr = t >> 6, lc = t & 63;
#pragma unroll
  for (int i = 0; i < 16; ++i) {
    const int row = i * 4 + lr;
    T[row][lc] = vw[(size_t)(by * 64 + row) * 1024 + bx * 64 + lc];
  }
  __syncthreads();
#pragma unroll
  for (int i = 0; i < 16; ++i) {
    const int row = i * 4 + lr;
    wvt[(size_t)(bx * 64 + row) * 1024 + by * 64 + lc] = f2h(T[lc][row]);
  }
}

// ---------------- b_eff[b][q] = dot(attT[b][q][:], v_b) --------------------
__global__ __launch_bounds__(256)
void beff_kernel(const unsigned short* __restrict__ attT, const float* __restrict__ vb,
                 float* __restrict__ beff) {
  const int b = blockIdx.y;
  const int q = blockIdx.x * 4 + (threadIdx.x >> 6);
  const int l = threadIdx.x & 63;
  const unsigned short* row = attT + ((size_t)b * 1024 + q) * 1024;
  float s = 0.0f;
#pragma unroll
  for (int i = 0; i < 2; ++i) {
    u16x8 v = *(const u16x8*)&row[(i * 64 + l) * 8];
    f32x4 vb0 = *(const f32x4*)&vb[(i * 64 + l) * 8];
    f32x4 vb1 = *(const f32x4*)&vb[(i * 64 + l) * 8 + 4];
#pragma unroll
    for (int j = 0; j < 4; j++) s += h2f(v[j]) * vb0[j];
#pragma unroll
    for (int j = 0; j < 4; j++) s += h2f(v[j + 4]) * vb1[j];
  }
#pragma unroll
  for (int o = 32; o > 0; o >>= 1) s += __shfl_down(s, o);
  if (l == 0) beff[b * 1024 + q] = s;
}

// ================= value-path GEMM (f16, NT): C = A * B^T ==================
// 128x128 tile, BK=32, 256 thr, 4 waves (2x2), dbuf 32 KB, counted vmcnt(4).
// f16 outputs go through an LDS-staged epilogue (full-sector u16x8 stores).
// EPI: 1 f16 +bias[col] +gelu | 3 f32 +bias[col] +res16 (m2->out)
//      4 f16 plain (W_effT)   | 8 f16 +bias[col,per-z] +res16 (x1 alt)
template <int EPI>
__global__ __launch_bounds__(256)
void gemm_v(const unsigned short* __restrict__ Ain, const unsigned short* __restrict__ Bin,
            void* __restrict__ Cout, const float* __restrict__ bias,
            const unsigned short* __restrict__ res16In,
            int K, int lda, int ldb, int ldc,
            long long sA, long long sB, long long sC, long long sBias, long long sRes) {
  __shared__ short As[2][4096];   // 128x32 per buf
  __shared__ short Bs[2][4096];
  const int z = blockIdx.z;
  const unsigned short* A = Ain + (size_t)z * sA;
  const unsigned short* B = Bin + (size_t)z * sB;
  int bx = blockIdx.x, by = blockIdx.y;
  xcd_swz(bx, by, gridDim.x, gridDim.y);
  const int mBase = by * 128, nBase = bx * 128;
  const int t = threadIdx.x, w = t >> 6, l = t & 63;
  const int r16 = l & 15, kq = l >> 4;
  const int wr = (w >> 1) * 64, wc = (w & 1) * 64;
  f32x4 acc[4][4] = {};

  auto stage = [&](int buf, int k0) {  // 4 gload16 per wave
#pragma unroll
    for (int i = 0; i < 2; ++i) {
      const int c = i * 256 + t;                // 16B chunk in 128x32 tile
      const int row = c >> 2, cc = c & 3;
      const int gc = cc ^ ((row >> 1) & 3);     // source-side swizzle
      short* la = &As[buf][(i * 256 + w * 64) * 8];   // wave-uniform dst
      short* lb = &Bs[buf][(i * 256 + w * 64) * 8];
      gload16(&A[(size_t)(mBase + row) * lda + k0 + gc * 8], la);
      gload16(&B[(size_t)(nBase + row) * ldb + k0 + gc * 8], lb);
    }
  };

  const int nt = K >> 5;
  stage(0, 0);
  if (nt > 1) stage(1, 32);
  for (int ts = 0; ts < nt; ++ts) {
    const int cur = ts & 1;
    if (ts + 1 < nt) { asm volatile("s_waitcnt vmcnt(4)" ::: "memory"); }
    else             { asm volatile("s_waitcnt vmcnt(0)" ::: "memory"); }
    __builtin_amdgcn_s_barrier();
    FENCE();
    h16x8 aF[4], bF[4];
#pragma unroll
    for (int mi = 0; mi < 4; mi++) {
      const int r = wr + mi * 16 + r16;
      aF[mi] = *(const h16x8*)&As[cur][r * 32 + (kq ^ ((r >> 1) & 3)) * 8];
    }
#pragma unroll
    for (int ni = 0; ni < 4; ni++) {
      const int r = wc + ni * 16 + r16;
      bF[ni] = *(const h16x8*)&Bs[cur][r * 32 + (kq ^ ((r >> 1) & 3)) * 8];
    }
    __builtin_amdgcn_s_setprio(1);
#pragma unroll
    for (int mi = 0; mi < 4; mi++)
#pragma unroll
      for (int ni = 0; ni < 4; ni++)
        acc[mi][ni] = __builtin_amdgcn_mfma_f32_16x16x32_f16(aF[mi], bF[ni], acc[mi][ni], 0, 0, 0);
    __builtin_amdgcn_s_setprio(0);
    FENCE();
    __builtin_amdgcn_s_barrier();
    FENCE();
    if (ts + 2 < nt) stage(cur, (ts + 2) * 32);
  }
  FENCE();

  unsigned short* C16 = (unsigned short*)Cout + (size_t)z * sC;
  float* C32 = (float*)Cout + (size_t)z * sC;
  const float* bp = (EPI == 1 || EPI == 3 || EPI == 8) ? bias + (size_t)z * sBias : nullptr;
  const unsigned short* rp = (EPI == 3 || EPI == 8) ? res16In + (size_t)z * sRes : nullptr;

  if constexpr (EPI == 1 || EPI == 4 || EPI == 8) {
    // f16 out: per-wave 64x64 tile staged in (dead) As/Bs, coalesced stores.
    short* ep = ((w & 2) ? &Bs[0][0] : &As[0][0]) + (w & 1) * 4096;
#pragma unroll
    for (int mi = 0; mi < 4; mi++) {
#pragma unroll
      for (int ni = 0; ni < 4; ni++) {
        const int cl = nBase + wc + ni * 16 + r16;
        const float bcol = bp ? bp[cl] : 0.0f;
#pragma unroll
        for (int r = 0; r < 4; r++) {
          float v = acc[mi][ni][r] + bcol;
          if (EPI == 1) v = gelu_f(v);
          ep[(mi * 16 + kq * 4 + r) * 64 + ni * 16 + r16] = (short)f2h(v);
        }
      }
    }
#pragma unroll
    for (int j = 0; j < 8; j++) {
      const int f = j * 512 + l * 8;          // flat idx in 64x64 wave tile
      const int row = f >> 6, col = f & 63;
      u16x8 v8 = *(const u16x8*)&ep[f];
      const size_t gi = (size_t)(mBase + wr + row) * ldc + nBase + wc + col;
      if (EPI == 8) {
        u16x8 r8 = *(const u16x8*)&rp[gi];
#pragma unroll
        for (int q = 0; q < 8; q++) v8[q] = f2h(h2f(v8[q]) + h2f(r8[q]));
      }
      *(u16x8*)&C16[gi] = v8;
    }
  } else {  // EPI == 3: f32 out (full-sector already)
#pragma unroll
    for (int mi = 0; mi < 4; mi++) {
#pragma unroll
      for (int ni = 0; ni < 4; ni++) {
        const int cl = nBase + wc + ni * 16 + r16;
        const float bcol = bp[cl];
#pragma unroll
        for (int r = 0; r < 4; r++) {
          const int rw = mBase + wr + mi * 16 + kq * 4 + r;
          const size_t idx = (size_t)rw * ldc + cl;
          C32[idx] = acc[mi][ni][r] + bcol + h2f(rp[idx]);
        }
      }
    }
  }
}

// ================= x1 GEMM (REG-staged): f16 out + res(f16) ================
__global__ __launch_bounds__(256)
void gemm_r(const unsigned short* __restrict__ Ain, const unsigned short* __restrict__ Bin,
            unsigned short* __restrict__ Cout, const float* __restrict__ bias,
            const unsigned short* __restrict__ resIn,
            int K, int lda, int ldb, int ldc,
            long long sA, long long sB, long long sC, long long sBias, long long sRes) {
  __shared__ short As[2][4096];
  __shared__ short Bs[2][4096];
  const int z = blockIdx.z;
  const unsigned short* A = Ain + (size_t)z * sA;
  const unsigned short* B = Bin + (size_t)z * sB;
  int bx = blockIdx.x, by = blockIdx.y;
  xcd_swz(bx, by, gridDim.x, gridDim.y);
  const int mBase = by * 128, nBase = bx * 128;
  const int t = threadIdx.x, w = t >> 6, l = t & 63;
  const int r16 = l & 15, kq = l >> 4;
  const int wr = (w >> 1) * 64, wc = (w & 1) * 64;
  f32x4 acc[4][4] = {};

  const int row0 = t >> 2, row1 = 64 + (t >> 2);
  const int cc0 = t & 3;
  const int gc0 = cc0 ^ ((row0 >> 1) & 3);
  const int gc1 = cc0 ^ ((row1 >> 1) & 3);

  u16x8 ra0, ra1, rb0, rb1;
  auto loadreg = [&](int k0) {
    ra0 = *(const u16x8*)&A[(size_t)(mBase + row0) * lda + k0 + gc0 * 8];
    rb0 = *(const u16x8*)&B[(size_t)(nBase + row0) * ldb + k0 + gc0 * 8];
    ra1 = *(const u16x8*)&A[(size_t)(mBase + row1) * lda + k0 + gc1 * 8];
    rb1 = *(const u16x8*)&B[(size_t)(nBase + row1) * ldb + k0 + gc1 * 8];
  };
  auto dswrite = [&](int buf) {
    *(u16x8*)&As[buf][t * 8] = ra0;
    *(u16x8*)&Bs[buf][t * 8] = rb0;
    *(u16x8*)&As[buf][(256 + t) * 8] = ra1;
    *(u16x8*)&Bs[buf][(256 + t) * 8] = rb1;
  };

  const int nt = K >> 5;
  loadreg(0);
  dswrite(0);
  if (nt > 1) loadreg(32);
  asm volatile("s_waitcnt lgkmcnt(0)" ::: "memory");
  __builtin_amdgcn_s_barrier();
  FENCE();
  for (int ts = 0; ts < nt; ++ts) {
    const int cur = ts & 1;
    h16x8 aF[4], bF[4];
#pragma unroll
    for (int mi = 0; mi < 4; mi++) {
      const int r = wr + mi * 16 + r16;
      aF[mi] = *(const h16x8*)&As[cur][r * 32 + (kq ^ ((r >> 1) & 3)) * 8];
    }
#pragma unroll
    for (int ni = 0; ni < 4; ni++) {
      const int r = wc + ni * 16 + r16;
      bF[ni] = *(const h16x8*)&Bs[cur][r * 32 + (kq ^ ((r >> 1) & 3)) * 8];
    }
    __builtin_amdgcn_s_setprio(1);
#pragma unroll
    for (int mi = 0; mi < 4; mi++)
#pragma unroll
      for (int ni = 0; ni < 4; ni++)
        acc[mi][ni] = __builtin_amdgcn_mfma_f32_16x16x32_f16(aF[mi], bF[ni], acc[mi][ni], 0, 0, 0);
    __builtin_amdgcn_s_setprio(0);
    FENCE();
    if (ts + 1 < nt) {
      __builtin_amdgcn_s_barrier();
      FENCE();
      dswrite((ts + 1) & 1);
      if (ts + 2 < nt) loadreg((ts + 2) * 32);
      asm volatile("s_waitcnt lgkmcnt(0)" ::: "memory");
      FENCE();
      __builtin_amdgcn_s_barrier();
      FENCE();
    }
  }
  FENCE();

  unsigned short* C16 = Cout + (size_t)z * sC;
  const float* bp = bias + (size_t)z * sBias;
  const unsigned short* rp = resIn + (size_t)z * sRes;
  // LDS-staged f16 epilogue
  short* ep = ((w & 2) ? &Bs[0][0] : &As[0][0]) + (w & 1) * 4096;
#pragma unroll
  for (int mi = 0; mi < 4; mi++) {
#pragma unroll
    for (int ni = 0; ni < 4; ni++) {
      const int cl = nBase + wc + ni * 16 + r16;
      const float bcol = bp[cl];
#pragma unroll
      for (int r = 0; r < 4; r++)
        ep[(mi * 16 + kq * 4 + r) * 64 + ni * 16 + r16] =
            (short)f2h(acc[mi][ni][r] + bcol);
    }
  }
#pragma unroll
  for (int j = 0; j < 8; j++) {
    const int f = j * 512 + l * 8;
    const int row = f >> 6, col = f & 63;
    u16x8 v8 = *(const u16x8*)&ep[f];
    const size_t gi = (size_t)(mBase + wr + row) * ldc + nBase + wc + col;
    u16x8 r8 = *(const u16x8*)&rp[gi];
#pragma unroll
    for (int q = 0; q < 8; q++) v8[q] = f2h(h2f(v8[q]) + h2f(r8[q]));
    *(u16x8*)&C16[gi] = v8;
  }
}

// ================= m1 GEMM with FUSED LN2 on the A operand =================
// A = LN(x1h) applied on the fly (reg-staged, muis precomputed).
// out = f16 gelu(A_ln @ B^T + bias).
__global__ __launch_bounds__(256)
void gemm_m(const unsigned short* __restrict__ Ain, const unsigned short* __restrict__ Bin,
            const float* __restrict__ muis, const float* __restrict__ lng,
            const float* __restrict__ lnb, const float* __restrict__ bias,
            unsigned short* __restrict__ Cout, int K, int lda, int ldb, int ldc) {
  __shared__ short As[2][4096];
  __shared__ short Bs[2][4096];
  int bx = blockIdx.x, by = blockIdx.y;
  xcd_swz(bx, by, gridDim.x, gridDim.y);
  const int mBase = by * 128, nBase = bx * 128;
  const int t = threadIdx.x, w = t >> 6, l = t & 63;
  const int r16 = l & 15, kq = l >> 4;
  const int wr = (w >> 1) * 64, wc = (w & 1) * 64;
  f32x4 acc[4][4] = {};

  const int row0 = t >> 2, row1 = 64 + (t >> 2);
  const int cc0 = t & 3;
  const int gc0 = cc0 ^ ((row0 >> 1) & 3);
  const int gc1 = cc0 ^ ((row1 >> 1) & 3);
  const float mu0 = muis[(mBase + row0) * 2], is0 = muis[(mBase + row0) * 2 + 1];
  const float mu1 = muis[(mBase + row1) * 2], is1 = muis[(mBase + row1) * 2 + 1];

  u16x8 ra0, ra1, rb0, rb1;
  auto loadreg = [&](int k0) {
    ra0 = *(const u16x8*)&Ain[(size_t)(mBase + row0) * lda + k0 + gc0 * 8];
    rb0 = *(const u16x8*)&Bin[(size_t)(nBase + row0) * ldb + k0 + gc0 * 8];
    ra1 = *(const u16x8*)&Ain[(size_t)(mBase + row1) * lda + k0 + gc1 * 8];
    rb1 = *(const u16x8*)&Bin[(size_t)(nBase + row1) * ldb + k0 + gc1 * 8];
  };
  auto dswrite = [&](int buf, int k0) {
    {
      const int cb = k0 + gc0 * 8;
      f32x4 g0 = *(const f32x4*)&lng[cb], g1 = *(const f32x4*)&lng[cb + 4];
      f32x4 b0 = *(const f32x4*)&lnb[cb], b1 = *(const f32x4*)&lnb[cb + 4];
      u16x8 o;
#pragma unroll
      for (int j = 0; j < 4; j++) o[j] = f2h((h2f(ra0[j]) - mu0) * is0 * g0[j] + b0[j]);
#pragma unroll
      for (int j = 0; j < 4; j++) o[j + 4] = f2h((h2f(ra0[j + 4]) - mu0) * is0 * g1[j] + b1[j]);
      *(u16x8*)&As[buf][t * 8] = o;
      *(u16x8*)&Bs[buf][t * 8] = rb0;
    }
    {
      const int cb = k0 + gc1 * 8;
      f32x4 g0 = *(const f32x4*)&lng[cb], g1 = *(const f32x4*)&lng[cb + 4];
      f32x4 b0 = *(const f32x4*)&lnb[cb], b1 = *(const f32x4*)&lnb[cb + 4];
      u16x8 o;
#pragma unroll
      for (int j = 0; j < 4; j++) o[j] = f2h((h2f(ra1[j]) - mu1) * is1 * g0[j] + b0[j]);
#pragma unroll
      for (int j = 0; j < 4; j++) o[j + 4] = f2h((h2f(ra1[j + 4]) - mu1) * is1 * g1[j] + b1[j]);
      *(u16x8*)&As[buf][(256 + t) * 8] = o;
      *(u16x8*)&Bs[buf][(256 + t) * 8] = rb1;
    }
  };

  const int nt = K >> 5;
  loadreg(0);
  dswrite(0, 0);
  if (nt > 1) loadreg(32);
  asm volatile("s_waitcnt lgkmcnt(0)" ::: "memory");
  __builtin_amdgcn_s_barrier();
  FENCE();
  for (int ts = 0; ts < nt; ++ts) {
    const int cur = ts & 1;
    h16x8 aF[4], bF[4];
#pragma unroll
    for (int mi = 0; mi < 4; mi++) {
      const int r = wr + mi * 16 + r16;
      aF[mi] = *(const h16x8*)&As[cur][r * 32 + (kq ^ ((r >> 1) & 3)) * 8];
    }
#pragma unroll
    for (int ni = 0; ni < 4; ni++) {
      const int r = wc + ni * 16 + r16;
      bF[ni] = *(const h16x8*)&Bs[cur][r * 32 + (kq ^ ((r >> 1) & 3)) * 8];
    }
    __builtin_amdgcn_s_setprio(1);
#pragma unroll
    for (int mi = 0; mi < 4; mi++)
#pragma unroll
      for (int ni = 0; ni < 4; ni++)
        acc[mi][ni] = __builtin_amdgcn_mfma_f32_16x16x32_f16(aF[mi], bF[ni], acc[mi][ni], 0, 0, 0);
    __builtin_amdgcn_s_setprio(0);
    FENCE();
    if (ts + 1 < nt) {
      __builtin_amdgcn_s_barrier();
      FENCE();
      dswrite((ts + 1) & 1, (ts + 1) * 32);
      if (ts + 2 < nt) loadreg((ts + 2) * 32);
      asm volatile("s_waitcnt lgkmcnt(0)" ::: "memory");
      FENCE();
      __builtin_amdgcn_s_barrier();
      FENCE();
    }
  }
  FENCE();

  // f16 gelu epilogue, LDS-staged
  short* ep = ((w & 2) ? &Bs[0][0] : &As[0][0]) + (w & 1) * 4096;
#pragma unroll
  for (int mi = 0; mi < 4; mi++) {
#pragma unroll
    for (int ni = 0; ni < 4; ni++) {
      const int cl = nBase + wc + ni * 16 + r16;
      const float bcol = bias[cl];
#pragma unroll
      for (int r = 0; r < 4; r++)
        ep[(mi * 16 + kq * 4 + r) * 64 + ni * 16 + r16] =
            (short)f2h(gelu_f(acc[mi][ni][r] + bcol));
    }
  }
#pragma unroll
  for (int j = 0; j < 8; j++) {
    const int f = j * 512 + l * 8;
    const int row = f >> 6, col = f & 63;
    *(u16x8*)&Cout[(size_t)(mBase + wr + row) * ldc + nBase + wc + col] =
        *(const u16x8*)&ep[f];
  }
}

// ================= split-path GEMM: C = A(MxK) * B(NxK)^T ==================
// fp16-split hi/lo, 128x128 tile, BK=32, 4 waves (2x2), dbuf LDS (64 KB),
// counted vmcnt(8). SWAP=1: bx indexes M, by indexes N (Qt h-panel sharing).
// EPI: 4 f16 hi/lo out | 5 f32 out | 6 f16 hi/lo +bias[row] +gelu | 7 f32 +bias[row]
template <int EPI, int SWAP>
__global__ __launch_bounds__(256)
void gemm_s(const unsigned short* __restrict__ Ahi, const unsigned short* __restrict__ Alo,
            const unsigned short* __restrict__ Bhi, const unsigned short* __restrict__ Blo,
            void* __restrict__ Cout, unsigned short* __restrict__ Cout2,
            const float* __restrict__ bias,
            int K, int lda, int ldb, int ldc,
            long long sA, long long sB, long long sC, int splitK) {
  __shared__ short As[2][8192];   // [buf][plane(hi 0 / lo 4096)][128x32]
  __shared__ short Bs[2][8192];
  const int z = blockIdx.z;
  const int bi = z / splitK, sp = z % splitK;
  const int kLen = K / splitK, kStart = sp * kLen;
  const unsigned short* AH = Ahi + (size_t)bi * sA;
  const unsigned short* BH = Bhi + (size_t)bi * sB;
  const unsigned short* AL = Alo + (size_t)bi * sA;
  const unsigned short* BL = Blo + (size_t)bi * sB;
  int bx = blockIdx.x, by = blockIdx.y;
  xcd_swz(bx, by, gridDim.x, gridDim.y);
  const int mBase = (SWAP ? bx : by) * 128, nBase = (SWAP ? by : bx) * 128;
  const int t = threadIdx.x, w = t >> 6, l = t & 63;
  const int r16 = l & 15, kq = l >> 4;
  const int wr = (w >> 1) * 64, wc = (w & 1) * 64;
  f32x4 acc[4][4] = {};

  auto stage = [&](int buf, int k0) {   // 8 vector-mem instrs per wave
#pragma unroll
    for (int i = 0; i < 2; ++i) {
      const int c = i * 256 + t;             // chunk in 128x32 plane (512 chunks)
      const int row = c >> 2, cc = c & 3;
      const int gc = cc ^ ((row >> 1) & 3);  // source-side swizzle
      const int cbase = i * 256 + w * 64;    // wave-uniform
      const size_t ga = (size_t)(mBase + row) * lda + k0 + gc * 8;
      const size_t gb = (size_t)(nBase + row) * ldb + k0 + gc * 8;
      gload16(&AH[ga], &As[buf][cbase * 8]);
      gload16(&AL[ga], &As[buf][4096 + cbase * 8]);
      gload16(&BH[gb], &Bs[buf][cbase * 8]);
      gload16(&BL[gb], &Bs[buf][4096 + cbase * 8]);
    }
  };

  const int nsteps = kLen >> 5;
  stage(0, kStart);
  if (nsteps > 1) stage(1, kStart + 32);
  for (int ts = 0; ts < nsteps; ++ts) {
    const int cur = ts & 1;
    if (ts + 1 < nsteps) { asm volatile("s_waitcnt vmcnt(8)" ::: "memory"); }
    else                 { asm volatile("s_waitcnt vmcnt(0)" ::: "memory"); }
    __builtin_amdgcn_s_barrier();
    FENCE();
    h16x8 aH[4], bH[4], aL[4], bL[4];
#pragma unroll
    for (int mi = 0; mi < 4; mi++) {
      const int r = wr + mi * 16 + r16;
      const int off = r * 32 + (kq ^ ((r >> 1) & 3)) * 8;
      aH[mi] = *(const h16x8*)&As[cur][off];
      aL[mi] = *(const h16x8*)&As[cur][4096 + off];
    }
#pragma unroll
    for (int ni = 0; ni < 4; ni++) {
      const int r = wc + ni * 16 + r16;
      const int off = r * 32 + (kq ^ ((r >> 1) & 3)) * 8;
      bH[ni] = *(const h16x8*)&Bs[cur][off];
      bL[ni] = *(const h16x8*)&Bs[cur][4096 + off];
    }
    __builtin_amdgcn_s_setprio(1);
#pragma unroll
    for (int mi = 0; mi < 4; mi++)
#pragma unroll
      for (int ni = 0; ni < 4; ni++) {
        acc[mi][ni] = __builtin_amdgcn_mfma_f32_16x16x32_f16(aH[mi], bH[ni], acc[mi][ni], 0, 0, 0);
        acc[mi][ni] = __builtin_amdgcn_mfma_f32_16x16x32_f16(aH[mi], bL[ni], acc[mi][ni], 0, 0, 0);
        acc[mi][ni] = __builtin_amdgcn_mfma_f32_16x16x32_f16(aL[mi], bH[ni], acc[mi][ni], 0, 0, 0);
      }
    __builtin_amdgcn_s_setprio(0);
    FENCE();
    __builtin_amdgcn_s_barrier();
    FENCE();
    if (ts + 2 < nsteps) stage(cur, kStart + (ts + 2) * 32);
  }
  FENCE();

  unsigned short* C16 = (unsigned short*)Cout + (size_t)z * sC;
  unsigned short* C16b = Cout2 ? Cout2 + (size_t)z * sC : nullptr;
  float* C32 = (float*)Cout + (size_t)z * sC;

  if constexpr (EPI == 4 || EPI == 6) {
    short* ep = &As[0][0] + w * 4096;   // 8 KB per wave in dead As
    unsigned pk[4][4][4];
#pragma unroll
    for (int mi = 0; mi < 4; mi++)
#pragma unroll
      for (int ni = 0; ni < 4; ni++)
#pragma unroll
        for (int r = 0; r < 4; r++) {
          float v = acc[mi][ni][r];
          if (EPI == 6) { v += bias[mBase + wr + mi * 16 + kq * 4 + r]; v = gelu_f(v); }
          pk[mi][ni][r] = split16(v);
        }
#pragma unroll
    for (int mi = 0; mi < 4; mi++)
#pragma unroll
      for (int ni = 0; ni < 4; ni++)
#pragma unroll
        for (int r = 0; r < 4; r++)
          ep[(mi * 16 + kq * 4 + r) * 64 + ni * 16 + r16] =
              (short)(pk[mi][ni][r] & 0xffffu);
#pragma unroll
    for (int j = 0; j < 8; j++) {
      const int f = j * 512 + l * 8;
      const int row = f >> 6, col = f & 63;
      *(u16x8*)&C16[(size_t)(mBase + wr + row) * ldc + nBase + wc + col] =
          *(const u16x8*)&ep[f];
    }
#pragma unroll
    for (int mi = 0; mi < 4; mi++)
#pragma unroll
      for (int ni = 0; ni < 4; ni++)
#pragma unroll
        for (int r = 0; r < 4; r++)
          ep[(mi * 16 + kq * 4 + r) * 64 + ni * 16 + r16] =
              (short)(pk[mi][ni][r] >> 16);
#pragma unroll
    for (int j = 0; j < 8; j++) {
      const int f = j * 512 + l * 8;
      const int row = f >> 6, col = f & 63;
      *(u16x8*)&C16b[(size_t)(mBase + wr + row) * ldc + nBase + wc + col] =
          *(const u16x8*)&ep[f];
    }
  } else {
#pragma unroll
    for (int mi = 0; mi < 4; mi++) {
#pragma unroll
      for (int ni = 0; ni < 4; ni++) {
        const int cl = nBase + wc + ni * 16 + r16;
#pragma unroll
        for (int r = 0; r < 4; r++) {
          const int rw = mBase + wr + mi * 16 + kq * 4 + r;
          float v = acc[mi][ni][r];
          if (EPI == 7) v += bias[rw];
          C32[(size_t)rw * ldc + cl] = v;
        }
      }
    }
  }
}

// ---------------- energy split-K reduce -> f16 hi/lo -----------------------
__global__ __launch_bounds__(256)
void ereduce_kernel(const float* __restrict__ part, unsigned short* __restrict__ ehi,
                    unsigned short* __restrict__ elo) {
  const size_t idx = (size_t)blockIdx.x * 256 + threadIdx.x;  // 8*65536 total
  const size_t b = idx >> 16, i = idx & 65535;
  const float* p = part + b * (8ull * 65536) + i;
  float s0 = (p[0] + p[65536]) + (p[2 * 65536] + p[3 * 65536]);
  float s1 = (p[4 * 65536] + p[5 * 65536]) + (p[6 * 65536] + p[7 * 65536]);
  unsigned pk = split16(s0 + s1);
  ehi[idx] = (unsigned short)(pk & 0xffffu);
  elo[idx] = (unsigned short)(pk >> 16);
}

// ---------------- softmax over rows + transpose -> f16 ---------------------
__global__ __launch_bounds__(256)
void smax_t_kernel(const float* __restrict__ a2, unsigned short* __restrict__ attT) {
  __shared__ float S[8][1028];
  __shared__ float inv[8];
  const int t = threadIdx.x;
  const int b = blockIdx.y;
  const int o0 = blockIdx.x * 8;
  const float* src = a2 + ((size_t)b * 1024 + o0) * 1024;
#pragma unroll
  for (int i = 0; i < 8; i++)
    *(f32x4*)&S[i][t * 4] = *(const f32x4*)&src[(size_t)i * 1024 + t * 4];
  __syncthreads();
  const int w = t >> 6, l = t & 63;
  for (int rr = 0; rr < 2; rr++) {
    const int r = w * 2 + rr;
    float m = -1e30f;
#pragma unroll
    for (int i = 0; i < 16; i++) m = fmaxf(m, S[r][l + i * 64]);
#pragma unroll
    for (int o = 32; o > 0; o >>= 1) m = fmaxf(m, __shfl_xor(m, o));
    float ssum = 0.0f;
#pragma unroll
    for (int i = 0; i < 16; i++) {
      float e = expf(S[r][l + i * 64] - m);
      S[r][l + i * 64] = e;
      ssum += e;
    }
#pragma unroll
    for (int o = 32; o > 0; o >>= 1) ssum += __shfl_xor(ssum, o);
    if (l == 0) inv[r] = 1.0f / ssum;
  }
  __syncthreads();
  float iv[8];
#pragma unroll
  for (int r = 0; r < 8; r++) iv[r] = inv[r];
#pragma unroll
  for (int i = 0; i < 4; i++) {
    const int k = i * 256 + t;
    u16x8 ov;
#pragma unroll
    for (int r = 0; r < 8; r++) ov[r] = f2h(S[r][k] * iv[r]);
    *(u16x8*)&attT[((size_t)b * 1024 + k) * 1024 + o0] = ov;
  }
}

// ---------------------------------------------------------------------------
extern "C" void kernel_launch(void* const* d_in, const int* in_sizes, int n_in,
                              void* d_out, int out_size, void* d_ws, size_t ws_size,
                              hipStream_t stream) {
  (void)in_sizes; (void)n_in; (void)out_size; (void)ws_size;
  const float* x     = (const float*)d_in[1];
  const float* ln1_g = (const float*)d_in[2];
  const float* ln1_b = (const float*)d_in[3];
  const float* ln2_g = (const float*)d_in[4];
  const float* ln2_b = (const float*)d_in[5];
  const float* qk_w  = (const float*)d_in[6];
  const float* v_w   = (const float*)d_in[7];
  const float* v_b   = (const float*)d_in[8];
  const float* t1_w  = (const float*)d_in[9];
  const float* t1_b  = (const float*)d_in[10];
  const float* t2_w  = (const float*)d_in[11];
  const float* t2_b  = (const float*)d_in[12];
  const float* m1_w  = (const float*)d_in[13];
  const float* m1_b  = (const float*)d_in[14];
  const float* m2_w  = (const float*)d_in[15];
  const float* m2_b  = (const float*)d_in[16];

  char* ws = (char*)d_ws;
  unsigned short* hhi  = (unsigned short*)(ws + 0);            // 67 MB
  unsigned short* hlo  = (unsigned short*)(ws + 67108864);     // 67 MB (-> gb)
  unsigned short* Qthi = (unsigned short*)(ws + 134217728);    // 16.8 MB
  unsigned short* Qtlo = (unsigned short*)(ws + 150994944);    // 16.8 MB
  float*          part = (float*)(ws + 167772160);             // 16.8 MB
  unsigned short* Ehi  = (unsigned short*)(ws + 184549376);    // 1 MB
  unsigned short* Elo  = (unsigned short*)(ws + 185597952);    // 1 MB
  unsigned short* Ghi  = (unsigned short*)(ws + 186646528);    // 4.2 MB
  unsigned short* Glo  = (unsigned short*)(ws + 190840832);    // 4.2 MB
  float*          a2   = (float*)(ws + 195035136);             // 33.5 MB
  unsigned short* attT = (unsigned short*)(ws + 228589568);    // 16.8 MB
  unsigned short* WeT  = (unsigned short*)(ws + 245366784);    // 16.8 MB
  float*          beff = (float*)(ws + 262144000);             // 32 KB
  float*          muis = (float*)(ws + 262176768);             // 256 KB
  unsigned short* xh   = (unsigned short*)(ws + 268435456);    // 67 MB
  unsigned short* x1h  = (unsigned short*)(ws + 335544320);    // 67 MB
  unsigned short* wqh  = (unsigned short*)(ws + 446693376);    // 0.5 MB
  unsigned short* wql  = (unsigned short*)(ws + 447217664);
  unsigned short* wvt  = (unsigned short*)(ws + 447741952);    // 2 MB (transposed)
  unsigned short* wt1h = (unsigned short*)(ws + 449839104);
  unsigned short* wt1l = (unsigned short*)(ws + 450363392);
  unsigned short* wt2h = (unsigned short*)(ws + 450887680);
  unsigned short* wt2l = (unsigned short*)(ws + 451411968);
  unsigned short* wm1  = (unsigned short*)(ws + 451936256);    // 2 MB
  unsigned short* wm2  = (unsigned short*)(ws + 454033408);    // 2 MB
  unsigned short* gb = hlo;   // dead after Qt gemm
  float* out = (float*)d_out;

  // weight converts
  cvt_kernel<<<dim3(256),  dim3(256), 0, stream>>>(qk_w, wqh, wql, 65536);
  vwt_kernel<<<dim3(16, 16), dim3(256), 0, stream>>>(v_w, wvt);
  cvt_kernel<<<dim3(256),  dim3(256), 0, stream>>>(t1_w, wt1h, wt1l, 65536);
  cvt_kernel<<<dim3(256),  dim3(256), 0, stream>>>(t2_w, wt2h, wt2l, 65536);
  cvt_kernel<<<dim3(1024), dim3(256), 0, stream>>>(m1_w, wm1, nullptr, 262144);
  cvt_kernel<<<dim3(1024), dim3(256), 0, stream>>>(m2_w, wm2, nullptr, 262144);
  // h = LN1(x) -> hi/lo ; xh = f16(x)
  ln_kernel<<<dim3(32768), dim3(256), 0, stream>>>(x, ln1_g, ln1_b, hhi, hlo, xh);
  // Qt[b](256x4096) = qk_w @ h[b]^T  (split; SWAP grid: bx=M(2), by=N(32))
  gemm_s<4, 1><<<dim3(2, 32, 8), dim3(256), 0, stream>>>(
      wqh, wql, hhi, hlo, Qthi, Qtlo, nullptr,
      1024, 1024, 1024, 4096, 0, 4194304, 1048576, 1);
  // energy partials: part[b*8+s](256x256) = Qt[b] @ Qt[b]^T over k-chunk s
  gemm_s<5, 0><<<dim3(2, 2, 64), dim3(256), 0, stream>>>(
      Qthi, Qtlo, Qthi, Qtlo, part, nullptr, nullptr,
      4096, 4096, 4096, 256, 1048576, 1048576, 65536, 8);
  ereduce_kernel<<<dim3(2048), dim3(256), 0, stream>>>(part, Ehi, Elo);
  // G[b](1024x256) = gelu(t1_w @ en[b] + t1_b)  (en symmetric -> NT; split out)
  gemm_s<6, 0><<<dim3(2, 8, 8), dim3(256), 0, stream>>>(
      wt1h, wt1l, Ehi, Elo, Ghi, Glo, t1_b,
      256, 256, 256, 256, 0, 65536, 262144, 1);
  // a2[b](1024x1024) = t2_w @ G[b]^T + t2_b  (f32 out)
  gemm_s<7, 0><<<dim3(8, 8, 8), dim3(256), 0, stream>>>(
      wt2h, wt2l, Ghi, Glo, a2, nullptr, t2_b,
      256, 256, 256, 1024, 0, 262144, 1048576, 1);
  // attT[b] = softmax(a2[b], -1)^T  (f16)
  smax_t_kernel<<<dim3(128, 8), dim3(256), 0, stream>>>(a2, attT);
  // W_effT[b](1024x1024) = attT[b] @ wvt^T  (f16)
  gemm_v<4><<<dim3(8, 8, 8), dim3(256), 0, stream>>>(
      attT, wvt, WeT, nullptr, nullptr,
      1024, 1024, 1024, 1024, 1048576, 0, 1048576, 0, 0);
  // b_eff[b][q] = dot(attT[b][q,:], v_b)
  beff_kernel<<<dim3(256, 8), dim3(256), 0, stream>>>(attT, v_b, beff);
  // x1[b](4096x1024, f16) = hhi[b] @ W_effT[b]^T + b_eff[b] + xh[b]
  gemm_r<<<dim3(8, 32, 8), dim3(256), 0, stream>>>(
      hhi, WeT, x1h, beff, xh,
      1024, 1024, 1024, 1024, 4194304, 1048576, 4194304, 1024, 4194304);
  // LN2 stats from x1h
  stats16_kernel<<<dim3(32768), dim3(256), 0, stream>>>(x1h, muis);
  // g = gelu(LN2(x1) @ m1_w^T + m1_b)   (LN fused into staging)
  gemm_m<<<dim3(8, 256, 1), dim3(256), 0, stream>>>(
      x1h, wm1, muis, ln2_g, ln2_b, m1_b, gb, 1024, 1024, 1024, 1024);
  // out = x1 + g @ m2_w^T + m2_b (f32; res = f16 x1)
  gemm_v<3><<<dim3(8, 256, 1), dim3(256), 0, stream>>>(
      gb, wm2, out, m2_b, x1h, 1024, 1024, 1024, 1024, 0, 0, 0, 0, 0);
}

// Round 12
// 634.803 us; speedup vs baseline: 1.0411x; 1.0411x over previous
//
#include <hip/hip_runtime.h>

// ---------------------------------------------------------------------------
// Enhanced_transformer  B=8, N=4096, P=1024, P4=256  (all fp32 in/out)
//
// Logit path (Qt, energy, G, a2): fp16-SPLIT MFMA (hi+lo, 3 MFMA/pair).
// Value path: plain f16 MFMA; t_out folded: x1 = NT(h, W_effT)+b_eff+x.
// R12: LN2 folded into m1 EPILOGUE (not staging):
//   LN(x)@W^T = is*(x@W'^T - mu*S) + b2,  W'=m1_w*g, S=rowsum(W'),
//   b2=m1_b+m1_w@b.  m1 = plain f16 GEMM(x1h, W') + epilogue math.
//   (R11's in-staging LN was VALU-bound: 158us, VALUBusy 72%.)
// Qt grid-swap kept (R11 evidence: ~60us saved on h re-fetch).
// ---------------------------------------------------------------------------

typedef __attribute__((ext_vector_type(4))) float f32x4;
typedef __attribute__((ext_vector_type(8))) _Float16 h16x8;
typedef __attribute__((ext_vector_type(8))) unsigned short u16x8;
typedef __attribute__((ext_vector_type(4))) unsigned short u16x4;

__device__ __forceinline__ unsigned short f2h(float f) {
  _Float16 h = (_Float16)f;
  return __builtin_bit_cast(unsigned short, h);
}
__device__ __forceinline__ float h2f(unsigned short u) {
  return (float)__builtin_bit_cast(_Float16, u);
}
// returns hi in bits[15:0], lo in bits[31:16]
__device__ __forceinline__ unsigned split16(float f) {
  _Float16 h = (_Float16)f;
  _Float16 l = (_Float16)(f - (float)h);
  return (unsigned)__builtin_bit_cast(unsigned short, h) |
         ((unsigned)__builtin_bit_cast(unsigned short, l) << 16);
}
__device__ __forceinline__ float gelu_f(float x) {
  return 0.5f * x * (1.0f + erff(x * 0.70710678118654752f));
}
__device__ __forceinline__ void gload16(const void* g, void* l) {
  __builtin_amdgcn_global_load_lds(
      (const __attribute__((address_space(1))) unsigned int*)g,
      (__attribute__((address_space(3))) unsigned int*)l, 16, 0, 0);
}
#define FENCE() asm volatile("" ::: "memory")

// XCD chunk-swizzle, ROW-major flatten (bx fastest)
__device__ __forceinline__ void xcd_swz(int& bx, int& by, int gx, int gy) {
  const int nwg = gx * gy;
  if ((nwg & 7) == 0 && nwg >= 16) {
    const int flat = bx + gx * by;
    const int chunk = nwg >> 3;
    const int nf = (flat & 7) * chunk + (flat >> 3);
    bx = nf % gx;
    by = nf / gx;
  }
}

// ---------------- LayerNorm (f32 in): hi/lo f16 planes + raw xh f16 --------
__global__ __launch_bounds__(256)
void ln_kernel(const float* __restrict__ x, const float* __restrict__ g,
               const float* __restrict__ b, unsigned short* __restrict__ hi,
               unsigned short* __restrict__ lo, unsigned short* __restrict__ xh) {
  __shared__ float red[16];
  const size_t base = (size_t)blockIdx.x * 1024;
  const int t = threadIdx.x;
  f32x4 v = *(const f32x4*)&x[base + t * 4];
  float s = v[0] + v[1] + v[2] + v[3];
  float q = v[0] * v[0] + v[1] * v[1] + v[2] * v[2] + v[3] * v[3];
#pragma unroll
  for (int o = 32; o > 0; o >>= 1) { s += __shfl_down(s, o); q += __shfl_down(q, o); }
  const int w = t >> 6;
  if ((t & 63) == 0) { red[w] = s; red[8 + w] = q; }
  __syncthreads();
  s = (red[0] + red[1]) + (red[2] + red[3]);
  q = (red[8] + red[9]) + (red[10] + red[11]);
  const float mu = s * (1.0f / 1024.0f);
  const float var = q * (1.0f / 1024.0f) - mu * mu;
  const float is = rsqrtf(var + 1e-5f);
  f32x4 gg = *(const f32x4*)&g[t * 4];
  f32x4 bb = *(const f32x4*)&b[t * 4];
  u16x4 oh, ol, ox;
#pragma unroll
  for (int j = 0; j < 4; j++) {
    float y = (v[j] - mu) * is * gg[j] + bb[j];
    unsigned p = split16(y);
    oh[j] = (unsigned short)(p & 0xffffu);
    ol[j] = (unsigned short)(p >> 16);
    ox[j] = f2h(v[j]);
  }
  *(u16x4*)&hi[base + t * 4] = oh;
  if (lo) *(u16x4*)&lo[base + t * 4] = ol;
  if (xh) *(u16x4*)&xh[base + t * 4] = ox;
}

// ---------------- row stats (f16 in): muis[row] = {mu, rsig} ---------------
__global__ __launch_bounds__(256)
void stats16_kernel(const unsigned short* __restrict__ x16, float* __restrict__ muis) {
  __shared__ float red[16];
  const size_t base = (size_t)blockIdx.x * 1024;
  const int t = threadIdx.x;
  u16x4 raw = *(const u16x4*)&x16[base + t * 4];
  float v[4];
#pragma unroll
  for (int j = 0; j < 4; j++) v[j] = h2f(raw[j]);
  float s = v[0] + v[1] + v[2] + v[3];
  float q = v[0] * v[0] + v[1] * v[1] + v[2] * v[2] + v[3] * v[3];
#pragma unroll
  for (int o = 32; o > 0; o >>= 1) { s += __shfl_down(s, o); q += __shfl_down(q, o); }
  const int w = t >> 6;
  if ((t & 63) == 0) { red[w] = s; red[8 + w] = q; }
  __syncthreads();
  if (t == 0) {
    s = (red[0] + red[1]) + (red[2] + red[3]);
    q = (red[8] + red[9]) + (red[10] + red[11]);
    const float mu = s * (1.0f / 1024.0f);
    const float var = q * (1.0f / 1024.0f) - mu * mu;
    muis[blockIdx.x * 2] = mu;
    muis[blockIdx.x * 2 + 1] = rsqrtf(var + 1e-5f);
  }
}

// ---------------- fp32 -> f16 (hi + optional lo) ---------------------------
__global__ __launch_bounds__(256)
void cvt_kernel(const float* __restrict__ in, unsigned short* __restrict__ hi,
                unsigned short* __restrict__ lo, int n4) {
  int i = blockIdx.x * 256 + threadIdx.x;
  if (i < n4) {
    f32x4 v = *(const f32x4*)&in[(size_t)i * 4];
    u16x4 oh, ol;
#pragma unroll
    for (int j = 0; j < 4; j++) {
      unsigned p = split16(v[j]);
      oh[j] = (unsigned short)(p & 0xffffu);
      ol[j] = (unsigned short)(p >> 16);
    }
    *(u16x4*)&hi[(size_t)i * 4] = oh;
    if (lo) *(u16x4*)&lo[(size_t)i * 4] = ol;
  }
}

// ---------------- m1 prep: W' = m1_w*g (f16), S=rowsum(W'), b2=m1_b+m1_w@b --
__global__ __launch_bounds__(256)
void m1prep_kernel(const float* __restrict__ m1w, const float* __restrict__ lng,
                   const float* __restrict__ lnb, const float* __restrict__ m1b,
                   unsigned short* __restrict__ wp, float* __restrict__ S,
                   float* __restrict__ b2) {
  __shared__ float red[16];
  const int o = blockIdx.x;
  const int t = threadIdx.x;
  const float* row = m1w + (size_t)o * 1024;
  f32x4 wv = *(const f32x4*)&row[t * 4];
  f32x4 gv = *(const f32x4*)&lng[t * 4];
  f32x4 bv = *(const f32x4*)&lnb[t * 4];
  float s = 0.0f, d = 0.0f;
  u16x4 ow;
#pragma unroll
  for (int j = 0; j < 4; j++) {
    float wpj = wv[j] * gv[j];
    ow[j] = f2h(wpj);
    s += wpj;
    d += wv[j] * bv[j];
  }
  *(u16x4*)&wp[(size_t)o * 1024 + t * 4] = ow;
#pragma unroll
  for (int off = 32; off > 0; off >>= 1) { s += __shfl_down(s, off); d += __shfl_down(d, off); }
  const int w = t >> 6;
  if ((t & 63) == 0) { red[w] = s; red[8 + w] = d; }
  __syncthreads();
  if (t == 0) {
    S[o] = (red[0] + red[1]) + (red[2] + red[3]);
    b2[o] = m1b[o] + (red[8] + red[9]) + (red[10] + red[11]);
  }
}

// ---------------- v_w (f32, PxP) -> transposed f16 wv_t[j][p] --------------
__global__ __launch_bounds__(256)
void vwt_kernel(const float* __restrict__ vw, unsigned short* __restrict__ wvt) {
  __shared__ float T[64][65];
  const int bx = blockIdx.x, by = blockIdx.y;   // j-tile, p-tile
  const int t = threadIdx.x;
  const int lr = t >> 6, lc = t & 63;
#pragma unroll
  for (int i = 0; i < 16; ++i) {
    const int row = i * 4 + lr;
    T[row][lc] = vw[(size_t)(by * 64 + row) * 1024 + bx * 64 + lc];
  }
  __syncthreads();
#pragma unroll
  for (int i = 0; i < 16; ++i) {
    const int row = i * 4 + lr;
    wvt[(size_t)(bx * 64 + row) * 1024 + by * 64 + lc] = f2h(T[lc][row]);
  }
}

// ---------------- b_eff[b][q] = dot(attT[b][q][:], v_b) --------------------
__global__ __launch_bounds__(256)
void beff_kernel(const unsigned short* __restrict__ attT, const float* __restrict__ vb,
                 float* __restrict__ beff) {
  const int b = blockIdx.y;
  const int q = blockIdx.x * 4 + (threadIdx.x >> 6);
  const int l = threadIdx.x & 63;
  const unsigned short* row = attT + ((size_t)b * 1024 + q) * 1024;
  float s = 0.0f;
#pragma unroll
  for (int i = 0; i < 2; ++i) {
    u16x8 v = *(const u16x8*)&row[(i * 64 + l) * 8];
    f32x4 vb0 = *(const f32x4*)&vb[(i * 64 + l) * 8];
    f32x4 vb1 = *(const f32x4*)&vb[(i * 64 + l) * 8 + 4];
#pragma unroll
    for (int j = 0; j < 4; j++) s += h2f(v[j]) * vb0[j];
#pragma unroll
    for (int j = 0; j < 4; j++) s += h2f(v[j + 4]) * vb1[j];
  }
#pragma unroll
  for (int o = 32; o > 0; o >>= 1) s += __shfl_down(s, o);
  if (l == 0) beff[b * 1024 + q] = s;
}

// ================= value-path GEMM (f16, NT): C = A * B^T ==================
// 128x128 tile, BK=32, 256 thr, 4 waves (2x2), dbuf 32 KB, counted vmcnt(4).
// EPI: 1 f16 +bias[col] +gelu | 3 f32 +bias[col] +res16 (m2->out)
//      4 f16 plain (W_effT)   | 9 f16 gelu(is*(acc-mu*S)+b2)  (m1, LN-folded)
template <int EPI>
__global__ __launch_bounds__(256)
void gemm_v(const unsigned short* __restrict__ Ain, const unsigned short* __restrict__ Bin,
            void* __restrict__ Cout, const float* __restrict__ bias,
            const unsigned short* __restrict__ res16In, const float* __restrict__ muis,
            const float* __restrict__ Svec,
            int K, int lda, int ldb, int ldc,
            long long sA, long long sB, long long sC, long long sBias, long long sRes) {
  __shared__ short As[2][4096];   // 128x32 per buf
  __shared__ short Bs[2][4096];
  const int z = blockIdx.z;
  const unsigned short* A = Ain + (size_t)z * sA;
  const unsigned short* B = Bin + (size_t)z * sB;
  int bx = blockIdx.x, by = blockIdx.y;
  xcd_swz(bx, by, gridDim.x, gridDim.y);
  const int mBase = by * 128, nBase = bx * 128;
  const int t = threadIdx.x, w = t >> 6, l = t & 63;
  const int r16 = l & 15, kq = l >> 4;
  const int wr = (w >> 1) * 64, wc = (w & 1) * 64;
  f32x4 acc[4][4] = {};

  auto stage = [&](int buf, int k0) {  // 4 gload16 per wave
#pragma unroll
    for (int i = 0; i < 2; ++i) {
      const int c = i * 256 + t;                // 16B chunk in 128x32 tile
      const int row = c >> 2, cc = c & 3;
      const int gc = cc ^ ((row >> 1) & 3);     // source-side swizzle
      short* la = &As[buf][(i * 256 + w * 64) * 8];   // wave-uniform dst
      short* lb = &Bs[buf][(i * 256 + w * 64) * 8];
      gload16(&A[(size_t)(mBase + row) * lda + k0 + gc * 8], la);
      gload16(&B[(size_t)(nBase + row) * ldb + k0 + gc * 8], lb);
    }
  };

  const int nt = K >> 5;
  stage(0, 0);
  if (nt > 1) stage(1, 32);
  for (int ts = 0; ts < nt; ++ts) {
    const int cur = ts & 1;
    if (ts + 1 < nt) { asm volatile("s_waitcnt vmcnt(4)" ::: "memory"); }
    else             { asm volatile("s_waitcnt vmcnt(0)" ::: "memory"); }
    __builtin_amdgcn_s_barrier();
    FENCE();
    h16x8 aF[4], bF[4];
#pragma unroll
    for (int mi = 0; mi < 4; mi++) {
      const int r = wr + mi * 16 + r16;
      aF[mi] = *(const h16x8*)&As[cur][r * 32 + (kq ^ ((r >> 1) & 3)) * 8];
    }
#pragma unroll
    for (int ni = 0; ni < 4; ni++) {
      const int r = wc + ni * 16 + r16;
      bF[ni] = *(const h16x8*)&Bs[cur][r * 32 + (kq ^ ((r >> 1) & 3)) * 8];
    }
    __builtin_amdgcn_s_setprio(1);
#pragma unroll
    for (int mi = 0; mi < 4; mi++)
#pragma unroll
      for (int ni = 0; ni < 4; ni++)
        acc[mi][ni] = __builtin_amdgcn_mfma_f32_16x16x32_f16(aF[mi], bF[ni], acc[mi][ni], 0, 0, 0);
    __builtin_amdgcn_s_setprio(0);
    FENCE();
    __builtin_amdgcn_s_barrier();
    FENCE();
    if (ts + 2 < nt) stage(cur, (ts + 2) * 32);
  }
  FENCE();

  unsigned short* C16 = (unsigned short*)Cout + (size_t)z * sC;
  float* C32 = (float*)Cout + (size_t)z * sC;
  const float* bp = (EPI != 4) ? bias + (size_t)z * sBias : nullptr;
  const unsigned short* rp = (EPI == 3) ? res16In + (size_t)z * sRes : nullptr;

  if constexpr (EPI == 1 || EPI == 4 || EPI == 9) {
    // f16 out: per-wave 64x64 tile staged in (dead) As/Bs, coalesced stores.
    short* ep = ((w & 2) ? &Bs[0][0] : &As[0][0]) + (w & 1) * 4096;
#pragma unroll
    for (int mi = 0; mi < 4; mi++) {
      float mu[4], is[4];
      if (EPI == 9) {
#pragma unroll
        for (int r = 0; r < 4; r++) {
          const int rw = mBase + wr + mi * 16 + kq * 4 + r;
          mu[r] = muis[rw * 2];
          is[r] = muis[rw * 2 + 1];
        }
      }
#pragma unroll
      for (int ni = 0; ni < 4; ni++) {
        const int cl = nBase + wc + ni * 16 + r16;
        const float bcol = bp ? bp[cl] : 0.0f;
        const float Scol = (EPI == 9) ? Svec[cl] : 0.0f;
#pragma unroll
        for (int r = 0; r < 4; r++) {
          float v;
          if (EPI == 9) v = gelu_f(is[r] * (acc[mi][ni][r] - mu[r] * Scol) + bcol);
          else {
            v = acc[mi][ni][r] + bcol;
            if (EPI == 1) v = gelu_f(v);
          }
          ep[(mi * 16 + kq * 4 + r) * 64 + ni * 16 + r16] = (short)f2h(v);
        }
      }
    }
#pragma unroll
    for (int j = 0; j < 8; j++) {
      const int f = j * 512 + l * 8;          // flat idx in 64x64 wave tile
      const int row = f >> 6, col = f & 63;
      const size_t gi = (size_t)(mBase + wr + row) * ldc + nBase + wc + col;
      *(u16x8*)&C16[gi] = *(const u16x8*)&ep[f];
    }
  } else {  // EPI == 3: f32 out (full-sector already)
#pragma unroll
    for (int mi = 0; mi < 4; mi++) {
#pragma unroll
      for (int ni = 0; ni < 4; ni++) {
        const int cl = nBase + wc + ni * 16 + r16;
        const float bcol = bp[cl];
#pragma unroll
        for (int r = 0; r < 4; r++) {
          const int rw = mBase + wr + mi * 16 + kq * 4 + r;
          const size_t idx = (size_t)rw * ldc + cl;
          C32[idx] = acc[mi][ni][r] + bcol + h2f(rp[idx]);
        }
      }
    }
  }
}

// ================= x1 GEMM (REG-staged): f16 out + res(f16) ================
__global__ __launch_bounds__(256)
void gemm_r(const unsigned short* __restrict__ Ain, const unsigned short* __restrict__ Bin,
            unsigned short* __restrict__ Cout, const float* __restrict__ bias,
            const unsigned short* __restrict__ resIn,
            int K, int lda, int ldb, int ldc,
            long long sA, long long sB, long long sC, long long sBias, long long sRes) {
  __shared__ short As[2][4096];
  __shared__ short Bs[2][4096];
  const int z = blockIdx.z;
  const unsigned short* A = Ain + (size_t)z * sA;
  const unsigned short* B = Bin + (size_t)z * sB;
  int bx = blockIdx.x, by = blockIdx.y;
  xcd_swz(bx, by, gridDim.x, gridDim.y);
  const int mBase = by * 128, nBase = bx * 128;
  const int t = threadIdx.x, w = t >> 6, l = t & 63;
  const int r16 = l & 15, kq = l >> 4;
  const int wr = (w >> 1) * 64, wc = (w & 1) * 64;
  f32x4 acc[4][4] = {};

  const int row0 = t >> 2, row1 = 64 + (t >> 2);
  const int cc0 = t & 3;
  const int gc0 = cc0 ^ ((row0 >> 1) & 3);
  const int gc1 = cc0 ^ ((row1 >> 1) & 3);

  u16x8 ra0, ra1, rb0, rb1;
  auto loadreg = [&](int k0) {
    ra0 = *(const u16x8*)&A[(size_t)(mBase + row0) * lda + k0 + gc0 * 8];
    rb0 = *(const u16x8*)&B[(size_t)(nBase + row0) * ldb + k0 + gc0 * 8];
    ra1 = *(const u16x8*)&A[(size_t)(mBase + row1) * lda + k0 + gc1 * 8];
    rb1 = *(const u16x8*)&B[(size_t)(nBase + row1) * ldb + k0 + gc1 * 8];
  };
  auto dswrite = [&](int buf) {
    *(u16x8*)&As[buf][t * 8] = ra0;
    *(u16x8*)&Bs[buf][t * 8] = rb0;
    *(u16x8*)&As[buf][(256 + t) * 8] = ra1;
    *(u16x8*)&Bs[buf][(256 + t) * 8] = rb1;
  };

  const int nt = K >> 5;
  loadreg(0);
  dswrite(0);
  if (nt > 1) loadreg(32);
  asm volatile("s_waitcnt lgkmcnt(0)" ::: "memory");
  __builtin_amdgcn_s_barrier();
  FENCE();
  for (int ts = 0; ts < nt; ++ts) {
    const int cur = ts & 1;
    h16x8 aF[4], bF[4];
#pragma unroll
    for (int mi = 0; mi < 4; mi++) {
      const int r = wr + mi * 16 + r16;
      aF[mi] = *(const h16x8*)&As[cur][r * 32 + (kq ^ ((r >> 1) & 3)) * 8];
    }
#pragma unroll
    for (int ni = 0; ni < 4; ni++) {
      const int r = wc + ni * 16 + r16;
      bF[ni] = *(const h16x8*)&Bs[cur][r * 32 + (kq ^ ((r >> 1) & 3)) * 8];
    }
    __builtin_amdgcn_s_setprio(1);
#pragma unroll
    for (int mi = 0; mi < 4; mi++)
#pragma unroll
      for (int ni = 0; ni < 4; ni++)
        acc[mi][ni] = __builtin_amdgcn_mfma_f32_16x16x32_f16(aF[mi], bF[ni], acc[mi][ni], 0, 0, 0);
    __builtin_amdgcn_s_setprio(0);
    FENCE();
    if (ts + 1 < nt) {
      __builtin_amdgcn_s_barrier();
      FENCE();
      dswrite((ts + 1) & 1);
      if (ts + 2 < nt) loadreg((ts + 2) * 32);
      asm volatile("s_waitcnt lgkmcnt(0)" ::: "memory");
      FENCE();
      __builtin_amdgcn_s_barrier();
      FENCE();
    }
  }
  FENCE();

  unsigned short* C16 = Cout + (size_t)z * sC;
  const float* bp = bias + (size_t)z * sBias;
  const unsigned short* rp = resIn + (size_t)z * sRes;
  // LDS-staged f16 epilogue
  short* ep = ((w & 2) ? &Bs[0][0] : &As[0][0]) + (w & 1) * 4096;
#pragma unroll
  for (int mi = 0; mi < 4; mi++) {
#pragma unroll
    for (int ni = 0; ni < 4; ni++) {
      const int cl = nBase + wc + ni * 16 + r16;
      const float bcol = bp[cl];
#pragma unroll
      for (int r = 0; r < 4; r++)
        ep[(mi * 16 + kq * 4 + r) * 64 + ni * 16 + r16] =
            (short)f2h(acc[mi][ni][r] + bcol);
    }
  }
#pragma unroll
  for (int j = 0; j < 8; j++) {
    const int f = j * 512 + l * 8;
    const int row = f >> 6, col = f & 63;
    u16x8 v8 = *(const u16x8*)&ep[f];
    const size_t gi = (size_t)(mBase + wr + row) * ldc + nBase + wc + col;
    u16x8 r8 = *(const u16x8*)&rp[gi];
#pragma unroll
    for (int q = 0; q < 8; q++) v8[q] = f2h(h2f(v8[q]) + h2f(r8[q]));
    *(u16x8*)&C16[gi] = v8;
  }
}

// ================= split-path GEMM: C = A(MxK) * B(NxK)^T ==================
// fp16-split hi/lo, 128x128 tile, BK=32, 4 waves (2x2), dbuf LDS (64 KB),
// counted vmcnt(8). SWAP=1: bx indexes M, by indexes N (Qt h-panel sharing).
// EPI: 4 f16 hi/lo out | 5 f32 out | 6 f16 hi/lo +bias[row] +gelu | 7 f32 +bias[row]
template <int EPI, int SWAP>
__global__ __launch_bounds__(256)
void gemm_s(const unsigned short* __restrict__ Ahi, const unsigned short* __restrict__ Alo,
            const unsigned short* __restrict__ Bhi, const unsigned short* __restrict__ Blo,
            void* __restrict__ Cout, unsigned short* __restrict__ Cout2,
            const float* __restrict__ bias,
            int K, int lda, int ldb, int ldc,
            long long sA, long long sB, long long sC, int splitK) {
  __shared__ short As[2][8192];   // [buf][plane(hi 0 / lo 4096)][128x32]
  __shared__ short Bs[2][8192];
  const int z = blockIdx.z;
  const int bi = z / splitK, sp = z % splitK;
  const int kLen = K / splitK, kStart = sp * kLen;
  const unsigned short* AH = Ahi + (size_t)bi * sA;
  const unsigned short* BH = Bhi + (size_t)bi * sB;
  const unsigned short* AL = Alo + (size_t)bi * sA;
  const unsigned short* BL = Blo + (size_t)bi * sB;
  int bx = blockIdx.x, by = blockIdx.y;
  xcd_swz(bx, by, gridDim.x, gridDim.y);
  const int mBase = (SWAP ? bx : by) * 128, nBase = (SWAP ? by : bx) * 128;
  const int t = threadIdx.x, w = t >> 6, l = t & 63;
  const int r16 = l & 15, kq = l >> 4;
  const int wr = (w >> 1) * 64, wc = (w & 1) * 64;
  f32x4 acc[4][4] = {};

  auto stage = [&](int buf, int k0) {   // 8 vector-mem instrs per wave
#pragma unroll
    for (int i = 0; i < 2; ++i) {
      const int c = i * 256 + t;             // chunk in 128x32 plane (512 chunks)
      const int row = c >> 2, cc = c & 3;
      const int gc = cc ^ ((row >> 1) & 3);  // source-side swizzle
      const int cbase = i * 256 + w * 64;    // wave-uniform
      const size_t ga = (size_t)(mBase + row) * lda + k0 + gc * 8;
      const size_t gb = (size_t)(nBase + row) * ldb + k0 + gc * 8;
      gload16(&AH[ga], &As[buf][cbase * 8]);
      gload16(&AL[ga], &As[buf][4096 + cbase * 8]);
      gload16(&BH[gb], &Bs[buf][cbase * 8]);
      gload16(&BL[gb], &Bs[buf][4096 + cbase * 8]);
    }
  };

  const int nsteps = kLen >> 5;
  stage(0, kStart);
  if (nsteps > 1) stage(1, kStart + 32);
  for (int ts = 0; ts < nsteps; ++ts) {
    const int cur = ts & 1;
    if (ts + 1 < nsteps) { asm volatile("s_waitcnt vmcnt(8)" ::: "memory"); }
    else                 { asm volatile("s_waitcnt vmcnt(0)" ::: "memory"); }
    __builtin_amdgcn_s_barrier();
    FENCE();
    h16x8 aH[4], bH[4], aL[4], bL[4];
#pragma unroll
    for (int mi = 0; mi < 4; mi++) {
      const int r = wr + mi * 16 + r16;
      const int off = r * 32 + (kq ^ ((r >> 1) & 3)) * 8;
      aH[mi] = *(const h16x8*)&As[cur][off];
      aL[mi] = *(const h16x8*)&As[cur][4096 + off];
    }
#pragma unroll
    for (int ni = 0; ni < 4; ni++) {
      const int r = wc + ni * 16 + r16;
      const int off = r * 32 + (kq ^ ((r >> 1) & 3)) * 8;
      bH[ni] = *(const h16x8*)&Bs[cur][off];
      bL[ni] = *(const h16x8*)&Bs[cur][4096 + off];
    }
    __builtin_amdgcn_s_setprio(1);
#pragma unroll
    for (int mi = 0; mi < 4; mi++)
#pragma unroll
      for (int ni = 0; ni < 4; ni++) {
        acc[mi][ni] = __builtin_amdgcn_mfma_f32_16x16x32_f16(aH[mi], bH[ni], acc[mi][ni], 0, 0, 0);
        acc[mi][ni] = __builtin_amdgcn_mfma_f32_16x16x32_f16(aH[mi], bL[ni], acc[mi][ni], 0, 0, 0);
        acc[mi][ni] = __builtin_amdgcn_mfma_f32_16x16x32_f16(aL[mi], bH[ni], acc[mi][ni], 0, 0, 0);
      }
    __builtin_amdgcn_s_setprio(0);
    FENCE();
    __builtin_amdgcn_s_barrier();
    FENCE();
    if (ts + 2 < nsteps) stage(cur, kStart + (ts + 2) * 32);
  }
  FENCE();

  unsigned short* C16 = (unsigned short*)Cout + (size_t)z * sC;
  unsigned short* C16b = Cout2 ? Cout2 + (size_t)z * sC : nullptr;
  float* C32 = (float*)Cout + (size_t)z * sC;

  if constexpr (EPI == 4 || EPI == 6) {
    short* ep = &As[0][0] + w * 4096;   // 8 KB per wave in dead As
    unsigned pk[4][4][4];
#pragma unroll
    for (int mi = 0; mi < 4; mi++)
#pragma unroll
      for (int ni = 0; ni < 4; ni++)
#pragma unroll
        for (int r = 0; r < 4; r++) {
          float v = acc[mi][ni][r];
          if (EPI == 6) { v += bias[mBase + wr + mi * 16 + kq * 4 + r]; v = gelu_f(v); }
          pk[mi][ni][r] = split16(v);
        }
#pragma unroll
    for (int mi = 0; mi < 4; mi++)
#pragma unroll
      for (int ni = 0; ni < 4; ni++)
#pragma unroll
        for (int r = 0; r < 4; r++)
          ep[(mi * 16 + kq * 4 + r) * 64 + ni * 16 + r16] =
              (short)(pk[mi][ni][r] & 0xffffu);
#pragma unroll
    for (int j = 0; j < 8; j++) {
      const int f = j * 512 + l * 8;
      const int row = f >> 6, col = f & 63;
      *(u16x8*)&C16[(size_t)(mBase + wr + row) * ldc + nBase + wc + col] =
          *(const u16x8*)&ep[f];
    }
#pragma unroll
    for (int mi = 0; mi < 4; mi++)
#pragma unroll
      for (int ni = 0; ni < 4; ni++)
#pragma unroll
        for (int r = 0; r < 4; r++)
          ep[(mi * 16 + kq * 4 + r) * 64 + ni * 16 + r16] =
              (short)(pk[mi][ni][r] >> 16);
#pragma unroll
    for (int j = 0; j < 8; j++) {
      const int f = j * 512 + l * 8;
      const int row = f >> 6, col = f & 63;
      *(u16x8*)&C16b[(size_t)(mBase + wr + row) * ldc + nBase + wc + col] =
          *(const u16x8*)&ep[f];
    }
  } else {
#pragma unroll
    for (int mi = 0; mi < 4; mi++) {
#pragma unroll
      for (int ni = 0; ni < 4; ni++) {
        const int cl = nBase + wc + ni * 16 + r16;
#pragma unroll
        for (int r = 0; r < 4; r++) {
          const int rw = mBase + wr + mi * 16 + kq * 4 + r;
          float v = acc[mi][ni][r];
          if (EPI == 7) v += bias[rw];
          C32[(size_t)rw * ldc + cl] = v;
        }
      }
    }
  }
}

// ---------------- energy split-K reduce -> f16 hi/lo -----------------------
__global__ __launch_bounds__(256)
void ereduce_kernel(const float* __restrict__ part, unsigned short* __restrict__ ehi,
                    unsigned short* __restrict__ elo) {
  const size_t idx = (size_t)blockIdx.x * 256 + threadIdx.x;  // 8*65536 total
  const size_t b = idx >> 16, i = idx & 65535;
  const float* p = part + b * (8ull * 65536) + i;
  float s0 = (p[0] + p[65536]) + (p[2 * 65536] + p[3 * 65536]);
  float s1 = (p[4 * 65536] + p[5 * 65536]) + (p[6 * 65536] + p[7 * 65536]);
  unsigned pk = split16(s0 + s1);
  ehi[idx] = (unsigned short)(pk & 0xffffu);
  elo[idx] = (unsigned short)(pk >> 16);
}

// ---------------- softmax over rows + transpose -> f16 ---------------------
__global__ __launch_bounds__(256)
void smax_t_kernel(const float* __restrict__ a2, unsigned short* __restrict__ attT) {
  __shared__ float S[8][1028];
  __shared__ float inv[8];
  const int t = threadIdx.x;
  const int b = blockIdx.y;
  const int o0 = blockIdx.x * 8;
  const float* src = a2 + ((size_t)b * 1024 + o0) * 1024;
#pragma unroll
  for (int i = 0; i < 8; i++)
    *(f32x4*)&S[i][t * 4] = *(const f32x4*)&src[(size_t)i * 1024 + t * 4];
  __syncthreads();
  const int w = t >> 6, l = t & 63;
  for (int rr = 0; rr < 2; rr++) {
    const int r = w * 2 + rr;
    float m = -1e30f;
#pragma unroll
    for (int i = 0; i < 16; i++) m = fmaxf(m, S[r][l + i * 64]);
#pragma unroll
    for (int o = 32; o > 0; o >>= 1) m = fmaxf(m, __shfl_xor(m, o));
    float ssum = 0.0f;
#pragma unroll
    for (int i = 0; i < 16; i++) {
      float e = expf(S[r][l + i * 64] - m);
      S[r][l + i * 64] = e;
      ssum += e;
    }
#pragma unroll
    for (int o = 32; o > 0; o >>= 1) ssum += __shfl_xor(ssum, o);
    if (l == 0) inv[r] = 1.0f / ssum;
  }
  __syncthreads();
  float iv[8];
#pragma unroll
  for (int r = 0; r < 8; r++) iv[r] = inv[r];
#pragma unroll
  for (int i = 0; i < 4; i++) {
    const int k = i * 256 + t;
    u16x8 ov;
#pragma unroll
    for (int r = 0; r < 8; r++) ov[r] = f2h(S[r][k] * iv[r]);
    *(u16x8*)&attT[((size_t)b * 1024 + k) * 1024 + o0] = ov;
  }
}

// ---------------------------------------------------------------------------
extern "C" void kernel_launch(void* const* d_in, const int* in_sizes, int n_in,
                              void* d_out, int out_size, void* d_ws, size_t ws_size,
                              hipStream_t stream) {
  (void)in_sizes; (void)n_in; (void)out_size; (void)ws_size;
  const float* x     = (const float*)d_in[1];
  const float* ln1_g = (const float*)d_in[2];
  const float* ln1_b = (const float*)d_in[3];
  const float* ln2_g = (const float*)d_in[4];
  const float* ln2_b = (const float*)d_in[5];
  const float* qk_w  = (const float*)d_in[6];
  const float* v_w   = (const float*)d_in[7];
  const float* v_b   = (const float*)d_in[8];
  const float* t1_w  = (const float*)d_in[9];
  const float* t1_b  = (const float*)d_in[10];
  const float* t2_w  = (const float*)d_in[11];
  const float* t2_b  = (const float*)d_in[12];
  const float* m1_w  = (const float*)d_in[13];
  const float* m1_b  = (const float*)d_in[14];
  const float* m2_w  = (const float*)d_in[15];
  const float* m2_b  = (const float*)d_in[16];

  char* ws = (char*)d_ws;
  unsigned short* hhi  = (unsigned short*)(ws + 0);            // 67 MB
  unsigned short* hlo  = (unsigned short*)(ws + 67108864);     // 67 MB (-> gb)
  unsigned short* Qthi = (unsigned short*)(ws + 134217728);    // 16.8 MB
  unsigned short* Qtlo = (unsigned short*)(ws + 150994944);    // 16.8 MB
  float*          part = (float*)(ws + 167772160);             // 16.8 MB
  unsigned short* Ehi  = (unsigned short*)(ws + 184549376);    // 1 MB
  unsigned short* Elo  = (unsigned short*)(ws + 185597952);    // 1 MB
  unsigned short* Ghi  = (unsigned short*)(ws + 186646528);    // 4.2 MB
  unsigned short* Glo  = (unsigned short*)(ws + 190840832);    // 4.2 MB
  float*          a2   = (float*)(ws + 195035136);             // 33.5 MB
  unsigned short* attT = (unsigned short*)(ws + 228589568);    // 16.8 MB
  unsigned short* WeT  = (unsigned short*)(ws + 245366784);    // 16.8 MB
  float*          beff = (float*)(ws + 262144000);             // 32 KB
  float*          muis = (float*)(ws + 262176768);             // 256 KB
  float*          Svec = (float*)(ws + 262438912);             // 4 KB
  float*          b2   = (float*)(ws + 262443008);             // 4 KB
  unsigned short* xh   = (unsigned short*)(ws + 268435456);    // 67 MB
  unsigned short* x1h  = (unsigned short*)(ws + 335544320);    // 67 MB
  unsigned short* wqh  = (unsigned short*)(ws + 446693376);    // 0.5 MB
  unsigned short* wql  = (unsigned short*)(ws + 447217664);
  unsigned short* wvt  = (unsigned short*)(ws + 447741952);    // 2 MB (transposed)
  unsigned short* wt1h = (unsigned short*)(ws + 449839104);
  unsigned short* wt1l = (unsigned short*)(ws + 450363392);
  unsigned short* wt2h = (unsigned short*)(ws + 450887680);
  unsigned short* wt2l = (unsigned short*)(ws + 451411968);
  unsigned short* wm1p = (unsigned short*)(ws + 451936256);    // 2 MB (m1_w * g)
  unsigned short* wm2  = (unsigned short*)(ws + 454033408);    // 2 MB
  unsigned short* gb = hlo;   // dead after Qt gemm
  float* out = (float*)d_out;

  // weight converts / prep
  cvt_kernel<<<dim3(256),  dim3(256), 0, stream>>>(qk_w, wqh, wql, 65536);
  vwt_kernel<<<dim3(16, 16), dim3(256), 0, stream>>>(v_w, wvt);
  cvt_kernel<<<dim3(256),  dim3(256), 0, stream>>>(t1_w, wt1h, wt1l, 65536);
  cvt_kernel<<<dim3(256),  dim3(256), 0, stream>>>(t2_w, wt2h, wt2l, 65536);
  m1prep_kernel<<<dim3(1024), dim3(256), 0, stream>>>(m1_w, ln2_g, ln2_b, m1_b, wm1p, Svec, b2);
  cvt_kernel<<<dim3(1024), dim3(256), 0, stream>>>(m2_w, wm2, nullptr, 262144);
  // h = LN1(x) -> hi/lo ; xh = f16(x)
  ln_kernel<<<dim3(32768), dim3(256), 0, stream>>>(x, ln1_g, ln1_b, hhi, hlo, xh);
  // Qt[b](256x4096) = qk_w @ h[b]^T  (split; SWAP grid: bx=M(2), by=N(32))
  gemm_s<4, 1><<<dim3(2, 32, 8), dim3(256), 0, stream>>>(
      wqh, wql, hhi, hlo, Qthi, Qtlo, nullptr,
      1024, 1024, 1024, 4096, 0, 4194304, 1048576, 1);
  // energy partials: part[b*8+s](256x256) = Qt[b] @ Qt[b]^T over k-chunk s
  gemm_s<5, 0><<<dim3(2, 2, 64), dim3(256), 0, stream>>>(
      Qthi, Qtlo, Qthi, Qtlo, part, nullptr, nullptr,
      4096, 4096, 4096, 256, 1048576, 1048576, 65536, 8);
  ereduce_kernel<<<dim3(2048), dim3(256), 0, stream>>>(part, Ehi, Elo);
  // G[b](1024x256) = gelu(t1_w @ en[b] + t1_b)  (en symmetric -> NT; split out)
  gemm_s<6, 0><<<dim3(2, 8, 8), dim3(256), 0, stream>>>(
      wt1h, wt1l, Ehi, Elo, Ghi, Glo, t1_b,
      256, 256, 256, 256, 0, 65536, 262144, 1);
  // a2[b](1024x1024) = t2_w @ G[b]^T + t2_b  (f32 out)
  gemm_s<7, 0><<<dim3(8, 8, 8), dim3(256), 0, stream>>>(
      wt2h, wt2l, Ghi, Glo, a2, nullptr, t2_b,
      256, 256, 256, 1024, 0, 262144, 1048576, 1);
  // attT[b] = softmax(a2[b], -1)^T  (f16)
  smax_t_kernel<<<dim3(128, 8), dim3(256), 0, stream>>>(a2, attT);
  // W_effT[b](1024x1024) = attT[b] @ wvt^T  (f16)
  gemm_v<4><<<dim3(8, 8, 8), dim3(256), 0, stream>>>(
      attT, wvt, WeT, nullptr, nullptr, nullptr, nullptr,
      1024, 1024, 1024, 1024, 1048576, 0, 1048576, 0, 0);
  // b_eff[b][q] = dot(attT[b][q,:], v_b)
  beff_kernel<<<dim3(256, 8), dim3(256), 0, stream>>>(attT, v_b, beff);
  // x1[b](4096x1024, f16) = hhi[b] @ W_effT[b]^T + b_eff[b] + xh[b]
  gemm_r<<<dim3(8, 32, 8), dim3(256), 0, stream>>>(
      hhi, WeT, x1h, beff, xh,
      1024, 1024, 1024, 1024, 4194304, 1048576, 4194304, 1024, 4194304);
  // LN2 stats from x1h
  stats16_kernel<<<dim3(32768), dim3(256), 0, stream>>>(x1h, muis);
  // g = gelu(is*(x1h @ wm1p^T - mu*S) + b2)   (LN folded into epilogue)
  gemm_v<9><<<dim3(8, 256, 1), dim3(256), 0, stream>>>(
      x1h, wm1p, gb, b2, nullptr, muis, Svec,
      1024, 1024, 1024, 1024, 0, 0, 0, 0, 0);
  // out = x1 + g @ m2_w^T + m2_b (f32; res = f16 x1)
  gemm_v<3><<<dim3(8, 256, 1), dim3(256), 0, stream>>>(
      gb, wm2, out, m2_b, x1h, nullptr, nullptr,
      1024, 1024, 1024, 1024, 0, 0, 0, 0, 0);
}

// Round 13
// 632.978 us; speedup vs baseline: 1.0441x; 1.0029x over previous
//
#include <hip/hip_runtime.h>

// ---------------------------------------------------------------------------
// Enhanced_transformer  B=8, N=4096, P=1024, P4=256  (all fp32 in/out)
//
// Logit path (Qt, energy, G, a2): fp16-SPLIT MFMA (hi+lo, 3 MFMA/pair).
// Value path: plain f16 MFMA; t_out folded: x1 = NT(x, g.W_effT)+corr+x.
// R13: LN1 folded OUT of the data path (same trick as R12's LN2 fold):
//   store only split16(x) + per-row (mu,is).  Qt = (qk_w.g)@x^T with
//   epilogue is_n*acc - is_n*mu_n*S[o] + B0[o];  x1 = x@(g.W_eff) with
//   epilogue is_n*(acc - mu_n*Sg[q]) + add1[q] + x.  Deletes h hi/lo + xh
//   (67 MB write) and makes x1's res read L2-hot (res == A rows).
// ---------------------------------------------------------------------------

typedef __attribute__((ext_vector_type(4))) float f32x4;
typedef __attribute__((ext_vector_type(8))) _Float16 h16x8;
typedef __attribute__((ext_vector_type(8))) unsigned short u16x8;
typedef __attribute__((ext_vector_type(4))) unsigned short u16x4;

__device__ __forceinline__ unsigned short f2h(float f) {
  _Float16 h = (_Float16)f;
  return __builtin_bit_cast(unsigned short, h);
}
__device__ __forceinline__ float h2f(unsigned short u) {
  return (float)__builtin_bit_cast(_Float16, u);
}
// returns hi in bits[15:0], lo in bits[31:16]
__device__ __forceinline__ unsigned split16(float f) {
  _Float16 h = (_Float16)f;
  _Float16 l = (_Float16)(f - (float)h);
  return (unsigned)__builtin_bit_cast(unsigned short, h) |
         ((unsigned)__builtin_bit_cast(unsigned short, l) << 16);
}
__device__ __forceinline__ float gelu_f(float x) {
  return 0.5f * x * (1.0f + erff(x * 0.70710678118654752f));
}
__device__ __forceinline__ void gload16(const void* g, void* l) {
  __builtin_amdgcn_global_load_lds(
      (const __attribute__((address_space(1))) unsigned int*)g,
      (__attribute__((address_space(3))) unsigned int*)l, 16, 0, 0);
}
#define FENCE() asm volatile("" ::: "memory")

// XCD chunk-swizzle, ROW-major flatten (bx fastest)
__device__ __forceinline__ void xcd_swz(int& bx, int& by, int gx, int gy) {
  const int nwg = gx * gy;
  if ((nwg & 7) == 0 && nwg >= 16) {
    const int flat = bx + gx * by;
    const int chunk = nwg >> 3;
    const int nf = (flat & 7) * chunk + (flat >> 3);
    bx = nf % gx;
    by = nf / gx;
  }
}

// ---------------- x -> split16(x) planes + per-row LN1 stats ---------------
__global__ __launch_bounds__(256)
void lnsplit_kernel(const float* __restrict__ x, unsigned short* __restrict__ xhi,
                    unsigned short* __restrict__ xlo, float* __restrict__ muis) {
  __shared__ float red[16];
  const size_t base = (size_t)blockIdx.x * 1024;
  const int t = threadIdx.x;
  f32x4 v = *(const f32x4*)&x[base + t * 4];
  float s = v[0] + v[1] + v[2] + v[3];
  float q = v[0] * v[0] + v[1] * v[1] + v[2] * v[2] + v[3] * v[3];
#pragma unroll
  for (int o = 32; o > 0; o >>= 1) { s += __shfl_down(s, o); q += __shfl_down(q, o); }
  const int w = t >> 6;
  if ((t & 63) == 0) { red[w] = s; red[8 + w] = q; }
  u16x4 oh, ol;
#pragma unroll
  for (int j = 0; j < 4; j++) {
    unsigned p = split16(v[j]);
    oh[j] = (unsigned short)(p & 0xffffu);
    ol[j] = (unsigned short)(p >> 16);
  }
  *(u16x4*)&xhi[base + t * 4] = oh;
  *(u16x4*)&xlo[base + t * 4] = ol;
  __syncthreads();
  if (t == 0) {
    s = (red[0] + red[1]) + (red[2] + red[3]);
    q = (red[8] + red[9]) + (red[10] + red[11]);
    const float mu = s * (1.0f / 1024.0f);
    const float var = q * (1.0f / 1024.0f) - mu * mu;
    muis[blockIdx.x * 2] = mu;
    muis[blockIdx.x * 2 + 1] = rsqrtf(var + 1e-5f);
  }
}

// ---------------- row stats (f16 in): muis[row] = {mu, rsig} ---------------
__global__ __launch_bounds__(256)
void stats16_kernel(const unsigned short* __restrict__ x16, float* __restrict__ muis) {
  __shared__ float red[16];
  const size_t base = (size_t)blockIdx.x * 1024;
  const int t = threadIdx.x;
  u16x4 raw = *(const u16x4*)&x16[base + t * 4];
  float v[4];
#pragma unroll
  for (int j = 0; j < 4; j++) v[j] = h2f(raw[j]);
  float s = v[0] + v[1] + v[2] + v[3];
  float q = v[0] * v[0] + v[1] * v[1] + v[2] * v[2] + v[3] * v[3];
#pragma unroll
  for (int o = 32; o > 0; o >>= 1) { s += __shfl_down(s, o); q += __shfl_down(q, o); }
  const int w = t >> 6;
  if ((t & 63) == 0) { red[w] = s; red[8 + w] = q; }
  __syncthreads();
  if (t == 0) {
    s = (red[0] + red[1]) + (red[2] + red[3]);
    q = (red[8] + red[9]) + (red[10] + red[11]);
    const float mu = s * (1.0f / 1024.0f);
    const float var = q * (1.0f / 1024.0f) - mu * mu;
    muis[blockIdx.x * 2] = mu;
    muis[blockIdx.x * 2 + 1] = rsqrtf(var + 1e-5f);
  }
}

// ---------------- fp32 -> f16 (hi + optional lo) ---------------------------
__global__ __launch_bounds__(256)
void cvt_kernel(const float* __restrict__ in, unsigned short* __restrict__ hi,
                unsigned short* __restrict__ lo, int n4) {
  int i = blockIdx.x * 256 + threadIdx.x;
  if (i < n4) {
    f32x4 v = *(const f32x4*)&in[(size_t)i * 4];
    u16x4 oh, ol;
#pragma unroll
    for (int j = 0; j < 4; j++) {
      unsigned p = split16(v[j]);
      oh[j] = (unsigned short)(p & 0xffffu);
      ol[j] = (unsigned short)(p >> 16);
    }
    *(u16x4*)&hi[(size_t)i * 4] = oh;
    if (lo) *(u16x4*)&lo[(size_t)i * 4] = ol;
  }
}

// ---------------- Qt prep: wq' = qk_w*g split, S=rowsum(wq'), B0=qk_w@b ----
__global__ __launch_bounds__(256)
void wqprep_kernel(const float* __restrict__ qkw, const float* __restrict__ lng,
                   const float* __restrict__ lnb, unsigned short* __restrict__ wh,
                   unsigned short* __restrict__ wl, float* __restrict__ S,
                   float* __restrict__ B0) {
  __shared__ float red[16];
  const int o = blockIdx.x;
  const int t = threadIdx.x;
  const float* row = qkw + (size_t)o * 1024;
  f32x4 wv = *(const f32x4*)&row[t * 4];
  f32x4 gv = *(const f32x4*)&lng[t * 4];
  f32x4 bv = *(const f32x4*)&lnb[t * 4];
  float s = 0.0f, d = 0.0f;
  u16x4 oh, ol;
#pragma unroll
  for (int j = 0; j < 4; j++) {
    float wg = wv[j] * gv[j];
    unsigned p = split16(wg);
    oh[j] = (unsigned short)(p & 0xffffu);
    ol[j] = (unsigned short)(p >> 16);
    s += wg;
    d += wv[j] * bv[j];
  }
  *(u16x4*)&wh[(size_t)o * 1024 + t * 4] = oh;
  *(u16x4*)&wl[(size_t)o * 1024 + t * 4] = ol;
#pragma unroll
  for (int off = 32; off > 0; off >>= 1) { s += __shfl_down(s, off); d += __shfl_down(d, off); }
  const int w = t >> 6;
  if ((t & 63) == 0) { red[w] = s; red[8 + w] = d; }
  __syncthreads();
  if (t == 0) {
    S[o] = (red[0] + red[1]) + (red[2] + red[3]);
    B0[o] = (red[8] + red[9]) + (red[10] + red[11]);
  }
}

// ---------------- m1 prep: W' = m1_w*g (f16), S=rowsum(W'), b2=m1_b+m1_w@b --
__global__ __launch_bounds__(256)
void m1prep_kernel(const float* __restrict__ m1w, const float* __restrict__ lng,
                   const float* __restrict__ lnb, const float* __restrict__ m1b,
                   unsigned short* __restrict__ wp, float* __restrict__ S,
                   float* __restrict__ b2) {
  __shared__ float red[16];
  const int o = blockIdx.x;
  const int t = threadIdx.x;
  const float* row = m1w + (size_t)o * 1024;
  f32x4 wv = *(const f32x4*)&row[t * 4];
  f32x4 gv = *(const f32x4*)&lng[t * 4];
  f32x4 bv = *(const f32x4*)&lnb[t * 4];
  float s = 0.0f, d = 0.0f;
  u16x4 ow;
#pragma unroll
  for (int j = 0; j < 4; j++) {
    float wpj = wv[j] * gv[j];
    ow[j] = f2h(wpj);
    s += wpj;
    d += wv[j] * bv[j];
  }
  *(u16x4*)&wp[(size_t)o * 1024 + t * 4] = ow;
#pragma unroll
  for (int off = 32; off > 0; off >>= 1) { s += __shfl_down(s, off); d += __shfl_down(d, off); }
  const int w = t >> 6;
  if ((t & 63) == 0) { red[w] = s; red[8 + w] = d; }
  __syncthreads();
  if (t == 0) {
    S[o] = (red[0] + red[1]) + (red[2] + red[3]);
    b2[o] = m1b[o] + (red[8] + red[9]) + (red[10] + red[11]);
  }
}

// ---------------- v_w vec dots: gv[p]=v_w[p,:]@g, vb2[p]=v_b[p]+v_w[p,:]@b --
__global__ __launch_bounds__(256)
void vwvec_kernel(const float* __restrict__ vw, const float* __restrict__ lng,
                  const float* __restrict__ lnb, const float* __restrict__ vb,
                  float* __restrict__ gv, float* __restrict__ vb2) {
  __shared__ float red[16];
  const int p = blockIdx.x;
  const int t = threadIdx.x;
  const float* row = vw + (size_t)p * 1024;
  f32x4 wv = *(const f32x4*)&row[t * 4];
  f32x4 gg = *(const f32x4*)&lng[t * 4];
  f32x4 bb = *(const f32x4*)&lnb[t * 4];
  float s = 0.0f, d = 0.0f;
#pragma unroll
  for (int j = 0; j < 4; j++) { s += wv[j] * gg[j]; d += wv[j] * bb[j]; }
#pragma unroll
  for (int off = 32; off > 0; off >>= 1) { s += __shfl_down(s, off); d += __shfl_down(d, off); }
  const int w = t >> 6;
  if ((t & 63) == 0) { red[w] = s; red[8 + w] = d; }
  __syncthreads();
  if (t == 0) {
    gv[p] = (red[0] + red[1]) + (red[2] + red[3]);
    vb2[p] = vb[p] + (red[8] + red[9]) + (red[10] + red[11]);
  }
}

// ---------------- v_w (f32, PxP) -> transposed f16 wvt[j][p] = v_w[p][j]*g[j]
__global__ __launch_bounds__(256)
void vwt_kernel(const float* __restrict__ vw, const float* __restrict__ lng,
                unsigned short* __restrict__ wvt) {
  __shared__ float T[64][65];
  const int bx = blockIdx.x, by = blockIdx.y;   // j-tile, p-tile
  const int t = threadIdx.x;
  const int lr = t >> 6, lc = t & 63;
#pragma unroll
  for (int i = 0; i < 16; ++i) {
    const int row = i * 4 + lr;
    T[row][lc] = vw[(size_t)(by * 64 + row) * 1024 + bx * 64 + lc];
  }
  __syncthreads();
#pragma unroll
  for (int i = 0; i < 16; ++i) {
    const int row = i * 4 + lr;
    wvt[(size_t)(bx * 64 + row) * 1024 + by * 64 + lc] =
        f2h(T[lc][row] * lng[bx * 64 + row]);
  }
}

// ---------------- att dots: add1[b][q]=attT_row@vb2, Sg[b][q]=attT_row@gv --
__global__ __launch_bounds__(256)
void attdots_kernel(const unsigned short* __restrict__ attT, const float* __restrict__ vb2,
                    const float* __restrict__ gv, float* __restrict__ add1,
                    float* __restrict__ Sg) {
  const int b = blockIdx.y;
  const int q = blockIdx.x * 4 + (threadIdx.x >> 6);
  const int l = threadIdx.x & 63;
  const unsigned short* row = attT + ((size_t)b * 1024 + q) * 1024;
  float s = 0.0f, d = 0.0f;
#pragma unroll
  for (int i = 0; i < 2; ++i) {
    u16x8 v = *(const u16x8*)&row[(i * 64 + l) * 8];
#pragma unroll
    for (int j = 0; j < 8; j++) {
      const float a = h2f(v[j]);
      const int idx = (i * 64 + l) * 8 + j;
      s += a * vb2[idx];
      d += a * gv[idx];
    }
  }
#pragma unroll
  for (int o = 32; o > 0; o >>= 1) { s += __shfl_down(s, o); d += __shfl_down(d, o); }
  if (l == 0) { add1[b * 1024 + q] = s; Sg[b * 1024 + q] = d; }
}

// ================= value-path GEMM (f16, NT): C = A * B^T ==================
// 128x128 tile, BK=32, 256 thr, 4 waves (2x2), dbuf 32 KB, counted vmcnt(4).
// EPI: 1 f16 +bias[col] +gelu | 3 f32 +bias[col] +res16 (m2->out)
//      4 f16 plain (W_effT)   | 9 f16 gelu(is*(acc-mu*S)+b2)  (m1, LN-folded)
template <int EPI>
__global__ __launch_bounds__(256)
void gemm_v(const unsigned short* __restrict__ Ain, const unsigned short* __restrict__ Bin,
            void* __restrict__ Cout, const float* __restrict__ bias,
            const unsigned short* __restrict__ res16In, const float* __restrict__ muis,
            const float* __restrict__ Svec,
            int K, int lda, int ldb, int ldc,
            long long sA, long long sB, long long sC, long long sBias, long long sRes) {
  __shared__ short As[2][4096];   // 128x32 per buf
  __shared__ short Bs[2][4096];
  const int z = blockIdx.z;
  const unsigned short* A = Ain + (size_t)z * sA;
  const unsigned short* B = Bin + (size_t)z * sB;
  int bx = blockIdx.x, by = blockIdx.y;
  xcd_swz(bx, by, gridDim.x, gridDim.y);
  const int mBase = by * 128, nBase = bx * 128;
  const int t = threadIdx.x, w = t >> 6, l = t & 63;
  const int r16 = l & 15, kq = l >> 4;
  const int wr = (w >> 1) * 64, wc = (w & 1) * 64;
  f32x4 acc[4][4] = {};

  auto stage = [&](int buf, int k0) {  // 4 gload16 per wave
#pragma unroll
    for (int i = 0; i < 2; ++i) {
      const int c = i * 256 + t;                // 16B chunk in 128x32 tile
      const int row = c >> 2, cc = c & 3;
      const int gc = cc ^ ((row >> 1) & 3);     // source-side swizzle
      short* la = &As[buf][(i * 256 + w * 64) * 8];   // wave-uniform dst
      short* lb = &Bs[buf][(i * 256 + w * 64) * 8];
      gload16(&A[(size_t)(mBase + row) * lda + k0 + gc * 8], la);
      gload16(&B[(size_t)(nBase + row) * ldb + k0 + gc * 8], lb);
    }
  };

  const int nt = K >> 5;
  stage(0, 0);
  if (nt > 1) stage(1, 32);
  for (int ts = 0; ts < nt; ++ts) {
    const int cur = ts & 1;
    if (ts + 1 < nt) { asm volatile("s_waitcnt vmcnt(4)" ::: "memory"); }
    else             { asm volatile("s_waitcnt vmcnt(0)" ::: "memory"); }
    __builtin_amdgcn_s_barrier();
    FENCE();
    h16x8 aF[4], bF[4];
#pragma unroll
    for (int mi = 0; mi < 4; mi++) {
      const int r = wr + mi * 16 + r16;
      aF[mi] = *(const h16x8*)&As[cur][r * 32 + (kq ^ ((r >> 1) & 3)) * 8];
    }
#pragma unroll
    for (int ni = 0; ni < 4; ni++) {
      const int r = wc + ni * 16 + r16;
      bF[ni] = *(const h16x8*)&Bs[cur][r * 32 + (kq ^ ((r >> 1) & 3)) * 8];
    }
    __builtin_amdgcn_s_setprio(1);
#pragma unroll
    for (int mi = 0; mi < 4; mi++)
#pragma unroll
      for (int ni = 0; ni < 4; ni++)
        acc[mi][ni] = __builtin_amdgcn_mfma_f32_16x16x32_f16(aF[mi], bF[ni], acc[mi][ni], 0, 0, 0);
    __builtin_amdgcn_s_setprio(0);
    FENCE();
    __builtin_amdgcn_s_barrier();
    FENCE();
    if (ts + 2 < nt) stage(cur, (ts + 2) * 32);
  }
  FENCE();

  unsigned short* C16 = (unsigned short*)Cout + (size_t)z * sC;
  float* C32 = (float*)Cout + (size_t)z * sC;
  const float* bp = (EPI != 4) ? bias + (size_t)z * sBias : nullptr;
  const unsigned short* rp = (EPI == 3) ? res16In + (size_t)z * sRes : nullptr;

  if constexpr (EPI == 1 || EPI == 4 || EPI == 9) {
    // f16 out: per-wave 64x64 tile staged in (dead) As/Bs, coalesced stores.
    short* ep = ((w & 2) ? &Bs[0][0] : &As[0][0]) + (w & 1) * 4096;
#pragma unroll
    for (int mi = 0; mi < 4; mi++) {
      float mu[4], is[4];
      if (EPI == 9) {
#pragma unroll
        for (int r = 0; r < 4; r++) {
          const int rw = mBase + wr + mi * 16 + kq * 4 + r;
          mu[r] = muis[rw * 2];
          is[r] = muis[rw * 2 + 1];
        }
      }
#pragma unroll
      for (int ni = 0; ni < 4; ni++) {
        const int cl = nBase + wc + ni * 16 + r16;
        const float bcol = bp ? bp[cl] : 0.0f;
        const float Scol = (EPI == 9) ? Svec[cl] : 0.0f;
#pragma unroll
        for (int r = 0; r < 4; r++) {
          float v;
          if (EPI == 9) v = gelu_f(is[r] * (acc[mi][ni][r] - mu[r] * Scol) + bcol);
          else {
            v = acc[mi][ni][r] + bcol;
            if (EPI == 1) v = gelu_f(v);
          }
          ep[(mi * 16 + kq * 4 + r) * 64 + ni * 16 + r16] = (short)f2h(v);
        }
      }
    }
#pragma unroll
    for (int j = 0; j < 8; j++) {
      const int f = j * 512 + l * 8;          // flat idx in 64x64 wave tile
      const int row = f >> 6, col = f & 63;
      const size_t gi = (size_t)(mBase + wr + row) * ldc + nBase + wc + col;
      *(u16x8*)&C16[gi] = *(const u16x8*)&ep[f];
    }
  } else {  // EPI == 3: f32 out (full-sector already)
#pragma unroll
    for (int mi = 0; mi < 4; mi++) {
#pragma unroll
      for (int ni = 0; ni < 4; ni++) {
        const int cl = nBase + wc + ni * 16 + r16;
        const float bcol = bp[cl];
#pragma unroll
        for (int r = 0; r < 4; r++) {
          const int rw = mBase + wr + mi * 16 + kq * 4 + r;
          const size_t idx = (size_t)rw * ldc + cl;
          C32[idx] = acc[mi][ni][r] + bcol + h2f(rp[idx]);
        }
      }
    }
  }
}

// ================= x1 GEMM (REG-staged, LN1-folded): f16 out ===============
// x1[n][q] = is_n*(acc - mu_n*Sg[q]) + add1[q] + x[n][q](res=xhi)
__global__ __launch_bounds__(256)
void gemm_r(const unsigned short* __restrict__ Ain, const unsigned short* __restrict__ Bin,
            unsigned short* __restrict__ Cout, const float* __restrict__ muis,
            const float* __restrict__ SgIn, const float* __restrict__ add1In,
            const unsigned short* __restrict__ resIn,
            int K, int lda, int ldb, int ldc,
            long long sA, long long sB, long long sC, long long sRes) {
  __shared__ short As[2][4096];
  __shared__ short Bs[2][4096];
  const int z = blockIdx.z;
  const unsigned short* A = Ain + (size_t)z * sA;
  const unsigned short* B = Bin + (size_t)z * sB;
  int bx = blockIdx.x, by = blockIdx.y;
  xcd_swz(bx, by, gridDim.x, gridDim.y);
  const int mBase = by * 128, nBase = bx * 128;
  const int t = threadIdx.x, w = t >> 6, l = t & 63;
  const int r16 = l & 15, kq = l >> 4;
  const int wr = (w >> 1) * 64, wc = (w & 1) * 64;
  f32x4 acc[4][4] = {};

  const int row0 = t >> 2, row1 = 64 + (t >> 2);
  const int cc0 = t & 3;
  const int gc0 = cc0 ^ ((row0 >> 1) & 3);
  const int gc1 = cc0 ^ ((row1 >> 1) & 3);

  u16x8 ra0, ra1, rb0, rb1;
  auto loadreg = [&](int k0) {
    ra0 = *(const u16x8*)&A[(size_t)(mBase + row0) * lda + k0 + gc0 * 8];
    rb0 = *(const u16x8*)&B[(size_t)(nBase + row0) * ldb + k0 + gc0 * 8];
    ra1 = *(const u16x8*)&A[(size_t)(mBase + row1) * lda + k0 + gc1 * 8];
    rb1 = *(const u16x8*)&B[(size_t)(nBase + row1) * ldb + k0 + gc1 * 8];
  };
  auto dswrite = [&](int buf) {
    *(u16x8*)&As[buf][t * 8] = ra0;
    *(u16x8*)&Bs[buf][t * 8] = rb0;
    *(u16x8*)&As[buf][(256 + t) * 8] = ra1;
    *(u16x8*)&Bs[buf][(256 + t) * 8] = rb1;
  };

  const int nt = K >> 5;
  loadreg(0);
  dswrite(0);
  if (nt > 1) loadreg(32);
  asm volatile("s_waitcnt lgkmcnt(0)" ::: "memory");
  __builtin_amdgcn_s_barrier();
  FENCE();
  for (int ts = 0; ts < nt; ++ts) {
    const int cur = ts & 1;
    h16x8 aF[4], bF[4];
#pragma unroll
    for (int mi = 0; mi < 4; mi++) {
      const int r = wr + mi * 16 + r16;
      aF[mi] = *(const h16x8*)&As[cur][r * 32 + (kq ^ ((r >> 1) & 3)) * 8];
    }
#pragma unroll
    for (int ni = 0; ni < 4; ni++) {
      const int r = wc + ni * 16 + r16;
      bF[ni] = *(const h16x8*)&Bs[cur][r * 32 + (kq ^ ((r >> 1) & 3)) * 8];
    }
    __builtin_amdgcn_s_setprio(1);
#pragma unroll
    for (int mi = 0; mi < 4; mi++)
#pragma unroll
      for (int ni = 0; ni < 4; ni++)
        acc[mi][ni] = __builtin_amdgcn_mfma_f32_16x16x32_f16(aF[mi], bF[ni], acc[mi][ni], 0, 0, 0);
    __builtin_amdgcn_s_setprio(0);
    FENCE();
    if (ts + 1 < nt) {
      __builtin_amdgcn_s_barrier();
      FENCE();
      dswrite((ts + 1) & 1);
      if (ts + 2 < nt) loadreg((ts + 2) * 32);
      asm volatile("s_waitcnt lgkmcnt(0)" ::: "memory");
      FENCE();
      __builtin_amdgcn_s_barrier();
      FENCE();
    }
  }
  FENCE();

  unsigned short* C16 = Cout + (size_t)z * sC;
  const float* muz = muis + (size_t)z * 8192;   // 4096 rows x {mu,is}
  const float* Sg = SgIn + (size_t)z * 1024;
  const float* ad = add1In + (size_t)z * 1024;
  const unsigned short* rp = resIn + (size_t)z * sRes;
  // LDS-staged f16 epilogue with LN1 corrections
  short* ep = ((w & 2) ? &Bs[0][0] : &As[0][0]) + (w & 1) * 4096;
#pragma unroll
  for (int mi = 0; mi < 4; mi++) {
    float mu[4], is[4];
#pragma unroll
    for (int r = 0; r < 4; r++) {
      const int rw = mBase + wr + mi * 16 + kq * 4 + r;
      mu[r] = muz[rw * 2];
      is[r] = muz[rw * 2 + 1];
    }
#pragma unroll
    for (int ni = 0; ni < 4; ni++) {
      const int cl = nBase + wc + ni * 16 + r16;
      const float sgc = Sg[cl];
      const float adc = ad[cl];
#pragma unroll
      for (int r = 0; r < 4; r++)
        ep[(mi * 16 + kq * 4 + r) * 64 + ni * 16 + r16] =
            (short)f2h(is[r] * (acc[mi][ni][r] - mu[r] * sgc) + adc);
    }
  }
#pragma unroll
  for (int j = 0; j < 8; j++) {
    const int f = j * 512 + l * 8;
    const int row = f >> 6, col = f & 63;
    u16x8 v8 = *(const u16x8*)&ep[f];
    const size_t gi = (size_t)(mBase + wr + row) * ldc + nBase + wc + col;
    u16x8 r8 = *(const u16x8*)&rp[gi];
#pragma unroll
    for (int q = 0; q < 8; q++) v8[q] = f2h(h2f(v8[q]) + h2f(r8[q]));
    *(u16x8*)&C16[gi] = v8;
  }
}

// ================= split-path GEMM: C = A(MxK) * B(NxK)^T ==================
// fp16-split hi/lo, 128x128 tile, BK=32, 4 waves (2x2), dbuf LDS (64 KB),
// counted vmcnt(8). SWAP=1: bx indexes M, by indexes N (Qt h-panel sharing).
// EPI: 5 f32 out | 6 f16 hi/lo +bias[row] +gelu | 7 f32 +bias[row]
//      10 f16 hi/lo, LN1-folded: is_c*acc - is_c*mu_c*S[row] + B0[row]  (Qt)
template <int EPI, int SWAP>
__global__ __launch_bounds__(256)
void gemm_s(const unsigned short* __restrict__ Ahi, const unsigned short* __restrict__ Alo,
            const unsigned short* __restrict__ Bhi, const unsigned short* __restrict__ Blo,
            void* __restrict__ Cout, unsigned short* __restrict__ Cout2,
            const float* __restrict__ bias, const float* __restrict__ B0vec,
            const float* __restrict__ mu1,
            int K, int lda, int ldb, int ldc,
            long long sA, long long sB, long long sC, int splitK) {
  __shared__ short As[2][8192];   // [buf][plane(hi 0 / lo 4096)][128x32]
  __shared__ short Bs[2][8192];
  const int z = blockIdx.z;
  const int bi = z / splitK, sp = z % splitK;
  const int kLen = K / splitK, kStart = sp * kLen;
  const unsigned short* AH = Ahi + (size_t)bi * sA;
  const unsigned short* BH = Bhi + (size_t)bi * sB;
  const unsigned short* AL = Alo + (size_t)bi * sA;
  const unsigned short* BL = Blo + (size_t)bi * sB;
  int bx = blockIdx.x, by = blockIdx.y;
  xcd_swz(bx, by, gridDim.x, gridDim.y);
  const int mBase = (SWAP ? bx : by) * 128, nBase = (SWAP ? by : bx) * 128;
  const int t = threadIdx.x, w = t >> 6, l = t & 63;
  const int r16 = l & 15, kq = l >> 4;
  const int wr = (w >> 1) * 64, wc = (w & 1) * 64;
  f32x4 acc[4][4] = {};

  auto stage = [&](int buf, int k0) {   // 8 vector-mem instrs per wave
#pragma unroll
    for (int i = 0; i < 2; ++i) {
      const int c = i * 256 + t;             // chunk in 128x32 plane (512 chunks)
      const int row = c >> 2, cc = c & 3;
      const int gc = cc ^ ((row >> 1) & 3);  // source-side swizzle
      const int cbase = i * 256 + w * 64;    // wave-uniform
      const size_t ga = (size_t)(mBase + row) * lda + k0 + gc * 8;
      const size_t gb = (size_t)(nBase + row) * ldb + k0 + gc * 8;
      gload16(&AH[ga], &As[buf][cbase * 8]);
      gload16(&AL[ga], &As[buf][4096 + cbase * 8]);
      gload16(&BH[gb], &Bs[buf][cbase * 8]);
      gload16(&BL[gb], &Bs[buf][4096 + cbase * 8]);
    }
  };

  const int nsteps = kLen >> 5;
  stage(0, kStart);
  if (nsteps > 1) stage(1, kStart + 32);
  for (int ts = 0; ts < nsteps; ++ts) {
    const int cur = ts & 1;
    if (ts + 1 < nsteps) { asm volatile("s_waitcnt vmcnt(8)" ::: "memory"); }
    else                 { asm volatile("s_waitcnt vmcnt(0)" ::: "memory"); }
    __builtin_amdgcn_s_barrier();
    FENCE();
    h16x8 aH[4], bH[4], aL[4], bL[4];
#pragma unroll
    for (int mi = 0; mi < 4; mi++) {
      const int r = wr + mi * 16 + r16;
      const int off = r * 32 + (kq ^ ((r >> 1) & 3)) * 8;
      aH[mi] = *(const h16x8*)&As[cur][off];
      aL[mi] = *(const h16x8*)&As[cur][4096 + off];
    }
#pragma unroll
    for (int ni = 0; ni < 4; ni++) {
      const int r = wc + ni * 16 + r16;
      const int off = r * 32 + (kq ^ ((r >> 1) & 3)) * 8;
      bH[ni] = *(const h16x8*)&Bs[cur][off];
      bL[ni] = *(const h16x8*)&Bs[cur][4096 + off];
    }
    __builtin_amdgcn_s_setprio(1);
#pragma unroll
    for (int mi = 0; mi < 4; mi++)
#pragma unroll
      for (int ni = 0; ni < 4; ni++) {
        acc[mi][ni] = __builtin_amdgcn_mfma_f32_16x16x32_f16(aH[mi], bH[ni], acc[mi][ni], 0, 0, 0);
        acc[mi][ni] = __builtin_amdgcn_mfma_f32_16x16x32_f16(aH[mi], bL[ni], acc[mi][ni], 0, 0, 0);
        acc[mi][ni] = __builtin_amdgcn_mfma_f32_16x16x32_f16(aL[mi], bH[ni], acc[mi][ni], 0, 0, 0);
      }
    __builtin_amdgcn_s_setprio(0);
    FENCE();
    __builtin_amdgcn_s_barrier();
    FENCE();
    if (ts + 2 < nsteps) stage(cur, kStart + (ts + 2) * 32);
  }
  FENCE();

  unsigned short* C16 = (unsigned short*)Cout + (size_t)z * sC;
  unsigned short* C16b = Cout2 ? Cout2 + (size_t)z * sC : nullptr;
  float* C32 = (float*)Cout + (size_t)z * sC;

  if constexpr (EPI == 6 || EPI == 10) {
    short* ep = &As[0][0] + w * 4096;   // 8 KB per wave in dead As
    const float* mu1b = (EPI == 10) ? mu1 + (size_t)bi * 8192 : nullptr;
    unsigned pk[4][4][4];
#pragma unroll
    for (int mi = 0; mi < 4; mi++)
#pragma unroll
      for (int ni = 0; ni < 4; ni++) {
        float muc = 0.f, isc = 0.f;
        if (EPI == 10) {
          const int cl = nBase + wc + ni * 16 + r16;
          muc = mu1b[cl * 2];
          isc = mu1b[cl * 2 + 1];
        }
#pragma unroll
        for (int r = 0; r < 4; r++) {
          const int rw = mBase + wr + mi * 16 + kq * 4 + r;
          float v = acc[mi][ni][r];
          if (EPI == 6) { v += bias[rw]; v = gelu_f(v); }
          if (EPI == 10) v = isc * (v - muc * bias[rw]) + B0vec[rw];  // bias=S
          pk[mi][ni][r] = split16(v);
        }
      }
#pragma unroll
    for (int mi = 0; mi < 4; mi++)
#pragma unroll
      for (int ni = 0; ni < 4; ni++)
#pragma unroll
        for (int r = 0; r < 4; r++)
          ep[(mi * 16 + kq * 4 + r) * 64 + ni * 16 + r16] =
              (short)(pk[mi][ni][r] & 0xffffu);
#pragma unroll
    for (int j = 0; j < 8; j++) {
      const int f = j * 512 + l * 8;
      const int row = f >> 6, col = f & 63;
      *(u16x8*)&C16[(size_t)(mBase + wr + row) * ldc + nBase + wc + col] =
          *(const u16x8*)&ep[f];
    }
#pragma unroll
    for (int mi = 0; mi < 4; mi++)
#pragma unroll
      for (int ni = 0; ni < 4; ni++)
#pragma unroll
        for (int r = 0; r < 4; r++)
          ep[(mi * 16 + kq * 4 + r) * 64 + ni * 16 + r16] =
              (short)(pk[mi][ni][r] >> 16);
#pragma unroll
    for (int j = 0; j < 8; j++) {
      const int f = j * 512 + l * 8;
      const int row = f >> 6, col = f & 63;
      *(u16x8*)&C16b[(size_t)(mBase + wr + row) * ldc + nBase + wc + col] =
          *(const u16x8*)&ep[f];
    }
  } else {
#pragma unroll
    for (int mi = 0; mi < 4; mi++) {
#pragma unroll
      for (int ni = 0; ni < 4; ni++) {
        const int cl = nBase + wc + ni * 16 + r16;
#pragma unroll
        for (int r = 0; r < 4; r++) {
          const int rw = mBase + wr + mi * 16 + kq * 4 + r;
          float v = acc[mi][ni][r];
          if (EPI == 7) v += bias[rw];
          C32[(size_t)rw * ldc + cl] = v;
        }
      }
    }
  }
}

// ---------------- energy split-K reduce -> f16 hi/lo -----------------------
__global__ __launch_bounds__(256)
void ereduce_kernel(const float* __restrict__ part, unsigned short* __restrict__ ehi,
                    unsigned short* __restrict__ elo) {
  const size_t idx = (size_t)blockIdx.x * 256 + threadIdx.x;  // 8*65536 total
  const size_t b = idx >> 16, i = idx & 65535;
  const float* p = part + b * (8ull * 65536) + i;
  float s0 = (p[0] + p[65536]) + (p[2 * 65536] + p[3 * 65536]);
  float s1 = (p[4 * 65536] + p[5 * 65536]) + (p[6 * 65536] + p[7 * 65536]);
  unsigned pk = split16(s0 + s1);
  ehi[idx] = (unsigned short)(pk & 0xffffu);
  elo[idx] = (unsigned short)(pk >> 16);
}

// ---------------- softmax over rows + transpose -> f16 ---------------------
__global__ __launch_bounds__(256)
void smax_t_kernel(const float* __restrict__ a2, unsigned short* __restrict__ attT) {
  __shared__ float S[8][1028];
  __shared__ float inv[8];
  const int t = threadIdx.x;
  const int b = blockIdx.y;
  const int o0 = blockIdx.x * 8;
  const float* src = a2 + ((size_t)b * 1024 + o0) * 1024;
#pragma unroll
  for (int i = 0; i < 8; i++)
    *(f32x4*)&S[i][t * 4] = *(const f32x4*)&src[(size_t)i * 1024 + t * 4];
  __syncthreads();
  const int w = t >> 6, l = t & 63;
  for (int rr = 0; rr < 2; rr++) {
    const int r = w * 2 + rr;
    float m = -1e30f;
#pragma unroll
    for (int i = 0; i < 16; i++) m = fmaxf(m, S[r][l + i * 64]);
#pragma unroll
    for (int o = 32; o > 0; o >>= 1) m = fmaxf(m, __shfl_xor(m, o));
    float ssum = 0.0f;
#pragma unroll
    for (int i = 0; i < 16; i++) {
      float e = expf(S[r][l + i * 64] - m);
      S[r][l + i * 64] = e;
      ssum += e;
    }
#pragma unroll
    for (int o = 32; o > 0; o >>= 1) ssum += __shfl_xor(ssum, o);
    if (l == 0) inv[r] = 1.0f / ssum;
  }
  __syncthreads();
  float iv[8];
#pragma unroll
  for (int r = 0; r < 8; r++) iv[r] = inv[r];
#pragma unroll
  for (int i = 0; i < 4; i++) {
    const int k = i * 256 + t;
    u16x8 ov;
#pragma unroll
    for (int r = 0; r < 8; r++) ov[r] = f2h(S[r][k] * iv[r]);
    *(u16x8*)&attT[((size_t)b * 1024 + k) * 1024 + o0] = ov;
  }
}

// ---------------------------------------------------------------------------
extern "C" void kernel_launch(void* const* d_in, const int* in_sizes, int n_in,
                              void* d_out, int out_size, void* d_ws, size_t ws_size,
                              hipStream_t stream) {
  (void)in_sizes; (void)n_in; (void)out_size; (void)ws_size;
  const float* x     = (const float*)d_in[1];
  const float* ln1_g = (const float*)d_in[2];
  const float* ln1_b = (const float*)d_in[3];
  const float* ln2_g = (const float*)d_in[4];
  const float* ln2_b = (const float*)d_in[5];
  const float* qk_w  = (const float*)d_in[6];
  const float* v_w   = (const float*)d_in[7];
  const float* v_b   = (const float*)d_in[8];
  const float* t1_w  = (const float*)d_in[9];
  const float* t1_b  = (const float*)d_in[10];
  const float* t2_w  = (const float*)d_in[11];
  const float* t2_b  = (const float*)d_in[12];
  const float* m1_w  = (const float*)d_in[13];
  const float* m1_b  = (const float*)d_in[14];
  const float* m2_w  = (const float*)d_in[15];
  const float* m2_b  = (const float*)d_in[16];

  char* ws = (char*)d_ws;
  unsigned short* xhi  = (unsigned short*)(ws + 0);            // 67 MB
  unsigned short* xlo  = (unsigned short*)(ws + 67108864);     // 67 MB (-> gb)
  unsigned short* Qthi = (unsigned short*)(ws + 134217728);    // 16.8 MB
  unsigned short* Qtlo = (unsigned short*)(ws + 150994944);    // 16.8 MB
  float*          part = (float*)(ws + 167772160);             // 16.8 MB
  unsigned short* Ehi  = (unsigned short*)(ws + 184549376);    // 1 MB
  unsigned short* Elo  = (unsigned short*)(ws + 185597952);    // 1 MB
  unsigned short* Ghi  = (unsigned short*)(ws + 186646528);    // 4.2 MB
  unsigned short* Glo  = (unsigned short*)(ws + 190840832);    // 4.2 MB
  float*          a2   = (float*)(ws + 195035136);             // 33.5 MB
  unsigned short* attT = (unsigned short*)(ws + 228589568);    // 16.8 MB
  unsigned short* WeT  = (unsigned short*)(ws + 245366784);    // 16.8 MB
  float*          add1 = (float*)(ws + 262144000);             // 32 KB
  float*          Sg   = (float*)(ws + 262176768);             // 32 KB
  float*          muis1= (float*)(ws + 262209536);             // 256 KB
  float*          muis2= (float*)(ws + 262471680);             // 256 KB
  float*          SvM1 = (float*)(ws + 262733824);             // 4 KB
  float*          b2   = (float*)(ws + 262737920);             // 4 KB
  float*          SQt  = (float*)(ws + 262742016);             // 1 KB
  float*          B0Qt = (float*)(ws + 262746112);             // 1 KB
  float*          gv   = (float*)(ws + 262750208);             // 4 KB
  float*          vb2  = (float*)(ws + 262754304);             // 4 KB
  unsigned short* x1h  = (unsigned short*)(ws + 335544320);    // 67 MB
  unsigned short* wqh  = (unsigned short*)(ws + 446693376);    // 0.5 MB
  unsigned short* wql  = (unsigned short*)(ws + 447217664);
  unsigned short* wvt  = (unsigned short*)(ws + 447741952);    // 2 MB (g-folded T)
  unsigned short* wt1h = (unsigned short*)(ws + 449839104);
  unsigned short* wt1l = (unsigned short*)(ws + 450363392);
  unsigned short* wt2h = (unsigned short*)(ws + 450887680);
  unsigned short* wt2l = (unsigned short*)(ws + 451411968);
  unsigned short* wm1p = (unsigned short*)(ws + 451936256);    // 2 MB (m1_w * g)
  unsigned short* wm2  = (unsigned short*)(ws + 454033408);    // 2 MB
  unsigned short* gb = xlo;   // dead after Qt gemm
  float* out = (float*)d_out;

  // weight converts / prep (LN1 folded into wq', wvt, gv/vb2)
  wqprep_kernel<<<dim3(256), dim3(256), 0, stream>>>(qk_w, ln1_g, ln1_b, wqh, wql, SQt, B0Qt);
  vwt_kernel<<<dim3(16, 16), dim3(256), 0, stream>>>(v_w, ln1_g, wvt);
  vwvec_kernel<<<dim3(1024), dim3(256), 0, stream>>>(v_w, ln1_g, ln1_b, v_b, gv, vb2);
  cvt_kernel<<<dim3(256),  dim3(256), 0, stream>>>(t1_w, wt1h, wt1l, 65536);
  cvt_kernel<<<dim3(256),  dim3(256), 0, stream>>>(t2_w, wt2h, wt2l, 65536);
  m1prep_kernel<<<dim3(1024), dim3(256), 0, stream>>>(m1_w, ln2_g, ln2_b, m1_b, wm1p, SvM1, b2);
  cvt_kernel<<<dim3(1024), dim3(256), 0, stream>>>(m2_w, wm2, nullptr, 262144);
  // x -> split planes + LN1 stats
  lnsplit_kernel<<<dim3(32768), dim3(256), 0, stream>>>(x, xhi, xlo, muis1);
  // Qt[b](256x4096) = (qk_w.g) @ x[b]^T, LN1-corrected epilogue (SWAP grid)
  gemm_s<10, 1><<<dim3(2, 32, 8), dim3(256), 0, stream>>>(
      wqh, wql, xhi, xlo, Qthi, Qtlo, SQt, B0Qt, muis1,
      1024, 1024, 1024, 4096, 0, 4194304, 1048576, 1);
  // energy partials: part[b*8+s](256x256) = Qt[b] @ Qt[b]^T over k-chunk s
  gemm_s<5, 0><<<dim3(2, 2, 64), dim3(256), 0, stream>>>(
      Qthi, Qtlo, Qthi, Qtlo, part, nullptr, nullptr, nullptr, nullptr,
      4096, 4096, 4096, 256, 1048576, 1048576, 65536, 8);
  ereduce_kernel<<<dim3(2048), dim3(256), 0, stream>>>(part, Ehi, Elo);
  // G[b](1024x256) = gelu(t1_w @ en[b] + t1_b)  (en symmetric -> NT; split out)
  gemm_s<6, 0><<<dim3(2, 8, 8), dim3(256), 0, stream>>>(
      wt1h, wt1l, Ehi, Elo, Ghi, Glo, t1_b, nullptr, nullptr,
      256, 256, 256, 256, 0, 65536, 262144, 1);
  // a2[b](1024x1024) = t2_w @ G[b]^T + t2_b  (f32 out)
  gemm_s<7, 0><<<dim3(8, 8, 8), dim3(256), 0, stream>>>(
      wt2h, wt2l, Ghi, Glo, a2, nullptr, t2_b, nullptr, nullptr,
      256, 256, 256, 1024, 0, 262144, 1048576, 1);
  // attT[b] = softmax(a2[b], -1)^T  (f16)
  smax_t_kernel<<<dim3(128, 8), dim3(256), 0, stream>>>(a2, attT);
  // WeT'[b](1024x1024) = attT[b] @ wvt^T  (g-folded, f16)
  gemm_v<4><<<dim3(8, 8, 8), dim3(256), 0, stream>>>(
      attT, wvt, WeT, nullptr, nullptr, nullptr, nullptr,
      1024, 1024, 1024, 1024, 1048576, 0, 1048576, 0, 0);
  // add1[b][q] = attT_row @ (v_b + v_w@b);  Sg[b][q] = attT_row @ (v_w@g)
  attdots_kernel<<<dim3(256, 8), dim3(256), 0, stream>>>(attT, vb2, gv, add1, Sg);
  // x1[b](4096x1024, f16) = is*(x@WeT' - mu*Sg) + add1 + x   (res = xhi)
  gemm_r<<<dim3(8, 32, 8), dim3(256), 0, stream>>>(
      xhi, WeT, x1h, muis1, Sg, add1, xhi,
      1024, 1024, 1024, 1024, 4194304, 1048576, 4194304, 4194304);
  // LN2 stats from x1h
  stats16_kernel<<<dim3(32768), dim3(256), 0, stream>>>(x1h, muis2);
  // g = gelu(is*(x1h @ wm1p^T - mu*S) + b2)   (LN2 folded into epilogue)
  gemm_v<9><<<dim3(8, 256, 1), dim3(256), 0, stream>>>(
      x1h, wm1p, gb, b2, nullptr, muis2, SvM1,
      1024, 1024, 1024, 1024, 0, 0, 0, 0, 0);
  // out = x1 + g @ m2_w^T + m2_b (f32; res = f16 x1)
  gemm_v<3><<<dim3(8, 256, 1), dim3(256), 0, stream>>>(
      gb, wm2, out, m2_b, x1h, nullptr, nullptr,
      1024, 1024, 1024, 1024, 0, 0, 0, 0, 0);
}

// Round 14
// 623.591 us; speedup vs baseline: 1.0598x; 1.0151x over previous
//
#include <hip/hip_runtime.h>

// ---------------------------------------------------------------------------
// Enhanced_transformer  B=8, N=4096, P=1024, P4=256  (all fp32 in/out)
//
// Logit path (Qt, energy, G, a2): fp16-SPLIT MFMA (hi+lo, 3 MFMA/pair).
// Value path: plain f16 MFMA; t_out folded: x1 = NT(x, g.W_effT)+corr+x.
// R14: xlo plane deleted. Qt (gemm_q) stages x as RAW F32 into LDS and
// splits hi/lo at fragment-read time (2x ds_read_b128 + cvt VALU, hidden
// under the step). lnsplit writes only xhi (-67 MB).
// Evidence base: all four NxP GEMMs pin at ~135us (509 TF) across 8
// schedule variants -> structure-bound at K=1024; only dispatch/byte
// deletion on streaming kernels still pays.
// ---------------------------------------------------------------------------

typedef __attribute__((ext_vector_type(4))) float f32x4;
typedef __attribute__((ext_vector_type(8))) _Float16 h16x8;
typedef __attribute__((ext_vector_type(8))) unsigned short u16x8;
typedef __attribute__((ext_vector_type(4))) unsigned short u16x4;

__device__ __forceinline__ unsigned short f2h(float f) {
  _Float16 h = (_Float16)f;
  return __builtin_bit_cast(unsigned short, h);
}
__device__ __forceinline__ float h2f(unsigned short u) {
  return (float)__builtin_bit_cast(_Float16, u);
}
// returns hi in bits[15:0], lo in bits[31:16]
__device__ __forceinline__ unsigned split16(float f) {
  _Float16 h = (_Float16)f;
  _Float16 l = (_Float16)(f - (float)h);
  return (unsigned)__builtin_bit_cast(unsigned short, h) |
         ((unsigned)__builtin_bit_cast(unsigned short, l) << 16);
}
__device__ __forceinline__ float gelu_f(float x) {
  return 0.5f * x * (1.0f + erff(x * 0.70710678118654752f));
}
__device__ __forceinline__ void gload16(const void* g, void* l) {
  __builtin_amdgcn_global_load_lds(
      (const __attribute__((address_space(1))) unsigned int*)g,
      (__attribute__((address_space(3))) unsigned int*)l, 16, 0, 0);
}
#define FENCE() asm volatile("" ::: "memory")

// XCD chunk-swizzle, ROW-major flatten (bx fastest)
__device__ __forceinline__ void xcd_swz(int& bx, int& by, int gx, int gy) {
  const int nwg = gx * gy;
  if ((nwg & 7) == 0 && nwg >= 16) {
    const int flat = bx + gx * by;
    const int chunk = nwg >> 3;
    const int nf = (flat & 7) * chunk + (flat >> 3);
    bx = nf % gx;
    by = nf / gx;
  }
}

// ---------------- x -> f16 hi plane + per-row LN1 stats --------------------
__global__ __launch_bounds__(256)
void lnsplit_kernel(const float* __restrict__ x, unsigned short* __restrict__ xhi,
                    float* __restrict__ muis) {
  __shared__ float red[16];
  const size_t base = (size_t)blockIdx.x * 1024;
  const int t = threadIdx.x;
  f32x4 v = *(const f32x4*)&x[base + t * 4];
  float s = v[0] + v[1] + v[2] + v[3];
  float q = v[0] * v[0] + v[1] * v[1] + v[2] * v[2] + v[3] * v[3];
#pragma unroll
  for (int o = 32; o > 0; o >>= 1) { s += __shfl_down(s, o); q += __shfl_down(q, o); }
  const int w = t >> 6;
  if ((t & 63) == 0) { red[w] = s; red[8 + w] = q; }
  u16x4 oh;
#pragma unroll
  for (int j = 0; j < 4; j++) oh[j] = f2h(v[j]);
  *(u16x4*)&xhi[base + t * 4] = oh;
  __syncthreads();
  if (t == 0) {
    s = (red[0] + red[1]) + (red[2] + red[3]);
    q = (red[8] + red[9]) + (red[10] + red[11]);
    const float mu = s * (1.0f / 1024.0f);
    const float var = q * (1.0f / 1024.0f) - mu * mu;
    muis[blockIdx.x * 2] = mu;
    muis[blockIdx.x * 2 + 1] = rsqrtf(var + 1e-5f);
  }
}

// ---------------- row stats (f16 in): muis[row] = {mu, rsig} ---------------
__global__ __launch_bounds__(256)
void stats16_kernel(const unsigned short* __restrict__ x16, float* __restrict__ muis) {
  __shared__ float red[16];
  const size_t base = (size_t)blockIdx.x * 1024;
  const int t = threadIdx.x;
  u16x4 raw = *(const u16x4*)&x16[base + t * 4];
  float v[4];
#pragma unroll
  for (int j = 0; j < 4; j++) v[j] = h2f(raw[j]);
  float s = v[0] + v[1] + v[2] + v[3];
  float q = v[0] * v[0] + v[1] * v[1] + v[2] * v[2] + v[3] * v[3];
#pragma unroll
  for (int o = 32; o > 0; o >>= 1) { s += __shfl_down(s, o); q += __shfl_down(q, o); }
  const int w = t >> 6;
  if ((t & 63) == 0) { red[w] = s; red[8 + w] = q; }
  __syncthreads();
  if (t == 0) {
    s = (red[0] + red[1]) + (red[2] + red[3]);
    q = (red[8] + red[9]) + (red[10] + red[11]);
    const float mu = s * (1.0f / 1024.0f);
    const float var = q * (1.0f / 1024.0f) - mu * mu;
    muis[blockIdx.x * 2] = mu;
    muis[blockIdx.x * 2 + 1] = rsqrtf(var + 1e-5f);
  }
}

// ---------------- fp32 -> f16 (hi + optional lo) ---------------------------
__global__ __launch_bounds__(256)
void cvt_kernel(const float* __restrict__ in, unsigned short* __restrict__ hi,
                unsigned short* __restrict__ lo, int n4) {
  int i = blockIdx.x * 256 + threadIdx.x;
  if (i < n4) {
    f32x4 v = *(const f32x4*)&in[(size_t)i * 4];
    u16x4 oh, ol;
#pragma unroll
    for (int j = 0; j < 4; j++) {
      unsigned p = split16(v[j]);
      oh[j] = (unsigned short)(p & 0xffffu);
      ol[j] = (unsigned short)(p >> 16);
    }
    *(u16x4*)&hi[(size_t)i * 4] = oh;
    if (lo) *(u16x4*)&lo[(size_t)i * 4] = ol;
  }
}

// ---------------- Qt prep: wq' = qk_w*g split, S=rowsum(wq'), B0=qk_w@b ----
__global__ __launch_bounds__(256)
void wqprep_kernel(const float* __restrict__ qkw, const float* __restrict__ lng,
                   const float* __restrict__ lnb, unsigned short* __restrict__ wh,
                   unsigned short* __restrict__ wl, float* __restrict__ S,
                   float* __restrict__ B0) {
  __shared__ float red[16];
  const int o = blockIdx.x;
  const int t = threadIdx.x;
  const float* row = qkw + (size_t)o * 1024;
  f32x4 wv = *(const f32x4*)&row[t * 4];
  f32x4 gv = *(const f32x4*)&lng[t * 4];
  f32x4 bv = *(const f32x4*)&lnb[t * 4];
  float s = 0.0f, d = 0.0f;
  u16x4 oh, ol;
#pragma unroll
  for (int j = 0; j < 4; j++) {
    float wg = wv[j] * gv[j];
    unsigned p = split16(wg);
    oh[j] = (unsigned short)(p & 0xffffu);
    ol[j] = (unsigned short)(p >> 16);
    s += wg;
    d += wv[j] * bv[j];
  }
  *(u16x4*)&wh[(size_t)o * 1024 + t * 4] = oh;
  *(u16x4*)&wl[(size_t)o * 1024 + t * 4] = ol;
#pragma unroll
  for (int off = 32; off > 0; off >>= 1) { s += __shfl_down(s, off); d += __shfl_down(d, off); }
  const int w = t >> 6;
  if ((t & 63) == 0) { red[w] = s; red[8 + w] = d; }
  __syncthreads();
  if (t == 0) {
    S[o] = (red[0] + red[1]) + (red[2] + red[3]);
    B0[o] = (red[8] + red[9]) + (red[10] + red[11]);
  }
}

// ---------------- m1 prep: W' = m1_w*g (f16), S=rowsum(W'), b2=m1_b+m1_w@b --
__global__ __launch_bounds__(256)
void m1prep_kernel(const float* __restrict__ m1w, const float* __restrict__ lng,
                   const float* __restrict__ lnb, const float* __restrict__ m1b,
                   unsigned short* __restrict__ wp, float* __restrict__ S,
                   float* __restrict__ b2) {
  __shared__ float red[16];
  const int o = blockIdx.x;
  const int t = threadIdx.x;
  const float* row = m1w + (size_t)o * 1024;
  f32x4 wv = *(const f32x4*)&row[t * 4];
  f32x4 gv = *(const f32x4*)&lng[t * 4];
  f32x4 bv = *(const f32x4*)&lnb[t * 4];
  float s = 0.0f, d = 0.0f;
  u16x4 ow;
#pragma unroll
  for (int j = 0; j < 4; j++) {
    float wpj = wv[j] * gv[j];
    ow[j] = f2h(wpj);
    s += wpj;
    d += wv[j] * bv[j];
  }
  *(u16x4*)&wp[(size_t)o * 1024 + t * 4] = ow;
#pragma unroll
  for (int off = 32; off > 0; off >>= 1) { s += __shfl_down(s, off); d += __shfl_down(d, off); }
  const int w = t >> 6;
  if ((t & 63) == 0) { red[w] = s; red[8 + w] = d; }
  __syncthreads();
  if (t == 0) {
    S[o] = (red[0] + red[1]) + (red[2] + red[3]);
    b2[o] = m1b[o] + (red[8] + red[9]) + (red[10] + red[11]);
  }
}

// ---------------- v_w vec dots: gv[p]=v_w[p,:]@g, vb2[p]=v_b[p]+v_w[p,:]@b --
__global__ __launch_bounds__(256)
void vwvec_kernel(const float* __restrict__ vw, const float* __restrict__ lng,
                  const float* __restrict__ lnb, const float* __restrict__ vb,
                  float* __restrict__ gv, float* __restrict__ vb2) {
  __shared__ float red[16];
  const int p = blockIdx.x;
  const int t = threadIdx.x;
  const float* row = vw + (size_t)p * 1024;
  f32x4 wv = *(const f32x4*)&row[t * 4];
  f32x4 gg = *(const f32x4*)&lng[t * 4];
  f32x4 bb = *(const f32x4*)&lnb[t * 4];
  float s = 0.0f, d = 0.0f;
#pragma unroll
  for (int j = 0; j < 4; j++) { s += wv[j] * gg[j]; d += wv[j] * bb[j]; }
#pragma unroll
  for (int off = 32; off > 0; off >>= 1) { s += __shfl_down(s, off); d += __shfl_down(d, off); }
  const int w = t >> 6;
  if ((t & 63) == 0) { red[w] = s; red[8 + w] = d; }
  __syncthreads();
  if (t == 0) {
    gv[p] = (red[0] + red[1]) + (red[2] + red[3]);
    vb2[p] = vb[p] + (red[8] + red[9]) + (red[10] + red[11]);
  }
}

// ---------------- v_w (f32, PxP) -> transposed f16 wvt[j][p] = v_w[p][j]*g[j]
__global__ __launch_bounds__(256)
void vwt_kernel(const float* __restrict__ vw, const float* __restrict__ lng,
                unsigned short* __restrict__ wvt) {
  __shared__ float T[64][65];
  const int bx = blockIdx.x, by = blockIdx.y;   // j-tile, p-tile
  const int t = threadIdx.x;
  const int lr = t >> 6, lc = t & 63;
#pragma unroll
  for (int i = 0; i < 16; ++i) {
    const int row = i * 4 + lr;
    T[row][lc] = vw[(size_t)(by * 64 + row) * 1024 + bx * 64 + lc];
  }
  __syncthreads();
#pragma unroll
  for (int i = 0; i < 16; ++i) {
    const int row = i * 4 + lr;
    wvt[(size_t)(bx * 64 + row) * 1024 + by * 64 + lc] =
        f2h(T[lc][row] * lng[bx * 64 + row]);
  }
}

// ---------------- att dots: add1[b][q]=attT_row@vb2, Sg[b][q]=attT_row@gv --
__global__ __launch_bounds__(256)
void attdots_kernel(const unsigned short* __restrict__ attT, const float* __restrict__ vb2,
                    const float* __restrict__ gv, float* __restrict__ add1,
                    float* __restrict__ Sg) {
  const int b = blockIdx.y;
  const int q = blockIdx.x * 4 + (threadIdx.x >> 6);
  const int l = threadIdx.x & 63;
  const unsigned short* row = attT + ((size_t)b * 1024 + q) * 1024;
  float s = 0.0f, d = 0.0f;
#pragma unroll
  for (int i = 0; i < 2; ++i) {
    u16x8 v = *(const u16x8*)&row[(i * 64 + l) * 8];
#pragma unroll
    for (int j = 0; j < 8; j++) {
      const float a = h2f(v[j]);
      const int idx = (i * 64 + l) * 8 + j;
      s += a * vb2[idx];
      d += a * gv[idx];
    }
  }
#pragma unroll
  for (int o = 32; o > 0; o >>= 1) { s += __shfl_down(s, o); d += __shfl_down(d, o); }
  if (l == 0) { add1[b * 1024 + q] = s; Sg[b * 1024 + q] = d; }
}

// ================= value-path GEMM (f16, NT): C = A * B^T ==================
// 128x128 tile, BK=32, 256 thr, 4 waves (2x2), dbuf 32 KB, counted vmcnt(4).
// EPI: 3 f32 +bias[col] +res16 (m2->out) | 4 f16 plain (W_effT)
//      9 f16 gelu(is*(acc-mu*S)+b2)  (m1, LN-folded)
template <int EPI>
__global__ __launch_bounds__(256)
void gemm_v(const unsigned short* __restrict__ Ain, const unsigned short* __restrict__ Bin,
            void* __restrict__ Cout, const float* __restrict__ bias,
            const unsigned short* __restrict__ res16In, const float* __restrict__ muis,
            const float* __restrict__ Svec,
            int K, int lda, int ldb, int ldc,
            long long sA, long long sB, long long sC, long long sBias, long long sRes) {
  __shared__ short As[2][4096];   // 128x32 per buf
  __shared__ short Bs[2][4096];
  const int z = blockIdx.z;
  const unsigned short* A = Ain + (size_t)z * sA;
  const unsigned short* B = Bin + (size_t)z * sB;
  int bx = blockIdx.x, by = blockIdx.y;
  xcd_swz(bx, by, gridDim.x, gridDim.y);
  const int mBase = by * 128, nBase = bx * 128;
  const int t = threadIdx.x, w = t >> 6, l = t & 63;
  const int r16 = l & 15, kq = l >> 4;
  const int wr = (w >> 1) * 64, wc = (w & 1) * 64;
  f32x4 acc[4][4] = {};

  auto stage = [&](int buf, int k0) {  // 4 gload16 per wave
#pragma unroll
    for (int i = 0; i < 2; ++i) {
      const int c = i * 256 + t;                // 16B chunk in 128x32 tile
      const int row = c >> 2, cc = c & 3;
      const int gc = cc ^ ((row >> 1) & 3);     // source-side swizzle
      short* la = &As[buf][(i * 256 + w * 64) * 8];   // wave-uniform dst
      short* lb = &Bs[buf][(i * 256 + w * 64) * 8];
      gload16(&A[(size_t)(mBase + row) * lda + k0 + gc * 8], la);
      gload16(&B[(size_t)(nBase + row) * ldb + k0 + gc * 8], lb);
    }
  };

  const int nt = K >> 5;
  stage(0, 0);
  if (nt > 1) stage(1, 32);
  for (int ts = 0; ts < nt; ++ts) {
    const int cur = ts & 1;
    if (ts + 1 < nt) { asm volatile("s_waitcnt vmcnt(4)" ::: "memory"); }
    else             { asm volatile("s_waitcnt vmcnt(0)" ::: "memory"); }
    __builtin_amdgcn_s_barrier();
    FENCE();
    h16x8 aF[4], bF[4];
#pragma unroll
    for (int mi = 0; mi < 4; mi++) {
      const int r = wr + mi * 16 + r16;
      aF[mi] = *(const h16x8*)&As[cur][r * 32 + (kq ^ ((r >> 1) & 3)) * 8];
    }
#pragma unroll
    for (int ni = 0; ni < 4; ni++) {
      const int r = wc + ni * 16 + r16;
      bF[ni] = *(const h16x8*)&Bs[cur][r * 32 + (kq ^ ((r >> 1) & 3)) * 8];
    }
    __builtin_amdgcn_s_setprio(1);
#pragma unroll
    for (int mi = 0; mi < 4; mi++)
#pragma unroll
      for (int ni = 0; ni < 4; ni++)
        acc[mi][ni] = __builtin_amdgcn_mfma_f32_16x16x32_f16(aF[mi], bF[ni], acc[mi][ni], 0, 0, 0);
    __builtin_amdgcn_s_setprio(0);
    FENCE();
    __builtin_amdgcn_s_barrier();
    FENCE();
    if (ts + 2 < nt) stage(cur, (ts + 2) * 32);
  }
  FENCE();

  unsigned short* C16 = (unsigned short*)Cout + (size_t)z * sC;
  float* C32 = (float*)Cout + (size_t)z * sC;
  const float* bp = (EPI != 4) ? bias + (size_t)z * sBias : nullptr;
  const unsigned short* rp = (EPI == 3) ? res16In + (size_t)z * sRes : nullptr;

  if constexpr (EPI == 4 || EPI == 9) {
    // f16 out: per-wave 64x64 tile staged in (dead) As/Bs, coalesced stores.
    short* ep = ((w & 2) ? &Bs[0][0] : &As[0][0]) + (w & 1) * 4096;
#pragma unroll
    for (int mi = 0; mi < 4; mi++) {
      float mu[4], is[4];
      if (EPI == 9) {
#pragma unroll
        for (int r = 0; r < 4; r++) {
          const int rw = mBase + wr + mi * 16 + kq * 4 + r;
          mu[r] = muis[rw * 2];
          is[r] = muis[rw * 2 + 1];
        }
      }
#pragma unroll
      for (int ni = 0; ni < 4; ni++) {
        const int cl = nBase + wc + ni * 16 + r16;
        const float bcol = bp ? bp[cl] : 0.0f;
        const float Scol = (EPI == 9) ? Svec[cl] : 0.0f;
#pragma unroll
        for (int r = 0; r < 4; r++) {
          float v;
          if (EPI == 9) v = gelu_f(is[r] * (acc[mi][ni][r] - mu[r] * Scol) + bcol);
          else          v = acc[mi][ni][r] + bcol;
          ep[(mi * 16 + kq * 4 + r) * 64 + ni * 16 + r16] = (short)f2h(v);
        }
      }
    }
#pragma unroll
    for (int j = 0; j < 8; j++) {
      const int f = j * 512 + l * 8;          // flat idx in 64x64 wave tile
      const int row = f >> 6, col = f & 63;
      const size_t gi = (size_t)(mBase + wr + row) * ldc + nBase + wc + col;
      *(u16x8*)&C16[gi] = *(const u16x8*)&ep[f];
    }
  } else {  // EPI == 3: f32 out (full-sector already)
#pragma unroll
    for (int mi = 0; mi < 4; mi++) {
#pragma unroll
      for (int ni = 0; ni < 4; ni++) {
        const int cl = nBase + wc + ni * 16 + r16;
        const float bcol = bp[cl];
#pragma unroll
        for (int r = 0; r < 4; r++) {
          const int rw = mBase + wr + mi * 16 + kq * 4 + r;
          const size_t idx = (size_t)rw * ldc + cl;
          C32[idx] = acc[mi][ni][r] + bcol + h2f(rp[idx]);
        }
      }
    }
  }
}

// ================= x1 GEMM (REG-staged, LN1-folded): f16 out ===============
// x1[n][q] = is_n*(acc - mu_n*Sg[q]) + add1[q] + x[n][q](res=xhi)
__global__ __launch_bounds__(256)
void gemm_r(const unsigned short* __restrict__ Ain, const unsigned short* __restrict__ Bin,
            unsigned short* __restrict__ Cout, const float* __restrict__ muis,
            const float* __restrict__ SgIn, const float* __restrict__ add1In,
            const unsigned short* __restrict__ resIn,
            int K, int lda, int ldb, int ldc,
            long long sA, long long sB, long long sC, long long sRes) {
  __shared__ short As[2][4096];
  __shared__ short Bs[2][4096];
  const int z = blockIdx.z;
  const unsigned short* A = Ain + (size_t)z * sA;
  const unsigned short* B = Bin + (size_t)z * sB;
  int bx = blockIdx.x, by = blockIdx.y;
  xcd_swz(bx, by, gridDim.x, gridDim.y);
  const int mBase = by * 128, nBase = bx * 128;
  const int t = threadIdx.x, w = t >> 6, l = t & 63;
  const int r16 = l & 15, kq = l >> 4;
  const int wr = (w >> 1) * 64, wc = (w & 1) * 64;
  f32x4 acc[4][4] = {};

  const int row0 = t >> 2, row1 = 64 + (t >> 2);
  const int cc0 = t & 3;
  const int gc0 = cc0 ^ ((row0 >> 1) & 3);
  const int gc1 = cc0 ^ ((row1 >> 1) & 3);

  u16x8 ra0, ra1, rb0, rb1;
  auto loadreg = [&](int k0) {
    ra0 = *(const u16x8*)&A[(size_t)(mBase + row0) * lda + k0 + gc0 * 8];
    rb0 = *(const u16x8*)&B[(size_t)(nBase + row0) * ldb + k0 + gc0 * 8];
    ra1 = *(const u16x8*)&A[(size_t)(mBase + row1) * lda + k0 + gc1 * 8];
    rb1 = *(const u16x8*)&B[(size_t)(nBase + row1) * ldb + k0 + gc1 * 8];
  };
  auto dswrite = [&](int buf) {
    *(u16x8*)&As[buf][t * 8] = ra0;
    *(u16x8*)&Bs[buf][t * 8] = rb0;
    *(u16x8*)&As[buf][(256 + t) * 8] = ra1;
    *(u16x8*)&Bs[buf][(256 + t) * 8] = rb1;
  };

  const int nt = K >> 5;
  loadreg(0);
  dswrite(0);
  if (nt > 1) loadreg(32);
  asm volatile("s_waitcnt lgkmcnt(0)" ::: "memory");
  __builtin_amdgcn_s_barrier();
  FENCE();
  for (int ts = 0; ts < nt; ++ts) {
    const int cur = ts & 1;
    h16x8 aF[4], bF[4];
#pragma unroll
    for (int mi = 0; mi < 4; mi++) {
      const int r = wr + mi * 16 + r16;
      aF[mi] = *(const h16x8*)&As[cur][r * 32 + (kq ^ ((r >> 1) & 3)) * 8];
    }
#pragma unroll
    for (int ni = 0; ni < 4; ni++) {
      const int r = wc + ni * 16 + r16;
      bF[ni] = *(const h16x8*)&Bs[cur][r * 32 + (kq ^ ((r >> 1) & 3)) * 8];
    }
    __builtin_amdgcn_s_setprio(1);
#pragma unroll
    for (int mi = 0; mi < 4; mi++)
#pragma unroll
      for (int ni = 0; ni < 4; ni++)
        acc[mi][ni] = __builtin_amdgcn_mfma_f32_16x16x32_f16(aF[mi], bF[ni], acc[mi][ni], 0, 0, 0);
    __builtin_amdgcn_s_setprio(0);
    FENCE();
    if (ts + 1 < nt) {
      __builtin_amdgcn_s_barrier();
      FENCE();
      dswrite((ts + 1) & 1);
      if (ts + 2 < nt) loadreg((ts + 2) * 32);
      asm volatile("s_waitcnt lgkmcnt(0)" ::: "memory");
      FENCE();
      __builtin_amdgcn_s_barrier();
      FENCE();
    }
  }
  FENCE();

  unsigned short* C16 = Cout + (size_t)z * sC;
  const float* muz = muis + (size_t)z * 8192;   // 4096 rows x {mu,is}
  const float* Sg = SgIn + (size_t)z * 1024;
  const float* ad = add1In + (size_t)z * 1024;
  const unsigned short* rp = resIn + (size_t)z * sRes;
  // LDS-staged f16 epilogue with LN1 corrections
  short* ep = ((w & 2) ? &Bs[0][0] : &As[0][0]) + (w & 1) * 4096;
#pragma unroll
  for (int mi = 0; mi < 4; mi++) {
    float mu[4], is[4];
#pragma unroll
    for (int r = 0; r < 4; r++) {
      const int rw = mBase + wr + mi * 16 + kq * 4 + r;
      mu[r] = muz[rw * 2];
      is[r] = muz[rw * 2 + 1];
    }
#pragma unroll
    for (int ni = 0; ni < 4; ni++) {
      const int cl = nBase + wc + ni * 16 + r16;
      const float sgc = Sg[cl];
      const float adc = ad[cl];
#pragma unroll
      for (int r = 0; r < 4; r++)
        ep[(mi * 16 + kq * 4 + r) * 64 + ni * 16 + r16] =
            (short)f2h(is[r] * (acc[mi][ni][r] - mu[r] * sgc) + adc);
    }
  }
#pragma unroll
  for (int j = 0; j < 8; j++) {
    const int f = j * 512 + l * 8;
    const int row = f >> 6, col = f & 63;
    u16x8 v8 = *(const u16x8*)&ep[f];
    const size_t gi = (size_t)(mBase + wr + row) * ldc + nBase + wc + col;
    u16x8 r8 = *(const u16x8*)&rp[gi];
#pragma unroll
    for (int q = 0; q < 8; q++) v8[q] = f2h(h2f(v8[q]) + h2f(r8[q]));
    *(u16x8*)&C16[gi] = v8;
  }
}

// ================= Qt GEMM: A = wq' hi/lo (f16), B = RAW F32 x =============
// 128x128, BK=32, dbuf; B staged as f32 into LDS (4 gload16), hi/lo split at
// fragment-read (2x ds_read_b128 f32 + cvt). Epilogue EPI-10 (LN1-folded).
// Grid SWAP: bx=M(2), by=N(32) for h-panel XCD sharing.
__global__ __launch_bounds__(256)
void gemm_q(const unsigned short* __restrict__ Ahi, const unsigned short* __restrict__ Alo,
            const float* __restrict__ Bf32,
            unsigned short* __restrict__ Cout, unsigned short* __restrict__ Cout2,
            const float* __restrict__ Svec, const float* __restrict__ B0vec,
            const float* __restrict__ mu1,
            int K, int lda, int ldb, int ldc,
            long long sB, long long sC) {
  __shared__ short As[2][8192];   // [buf][plane(hi 0 / lo 4096)][128x32]
  __shared__ float Bs[2][4096];   // [buf][128 rows][32 f32]
  const int z = blockIdx.z;
  const float* B = Bf32 + (size_t)z * sB;
  int bx = blockIdx.x, by = blockIdx.y;
  xcd_swz(bx, by, gridDim.x, gridDim.y);
  const int mBase = bx * 128, nBase = by * 128;   // SWAP roles
  const int t = threadIdx.x, w = t >> 6, l = t & 63;
  const int r16 = l & 15, kq = l >> 4;
  const int wr = (w >> 1) * 64, wc = (w & 1) * 64;
  f32x4 acc[4][4] = {};

  auto stage = [&](int buf, int k0) {   // 8 vector-mem instrs per wave
#pragma unroll
    for (int i = 0; i < 2; ++i) {       // A planes: 2 chunks each of hi/lo
      const int c = i * 256 + t;
      const int row = c >> 2, cc = c & 3;
      const int gc = cc ^ ((row >> 1) & 3);
      const int cbase = i * 256 + w * 64;
      const size_t ga = (size_t)(mBase + row) * lda + k0 + gc * 8;
      gload16(&Ahi[ga], &As[buf][cbase * 8]);
      gload16(&Alo[ga], &As[buf][4096 + cbase * 8]);
    }
#pragma unroll
    for (int i = 0; i < 4; ++i) {       // B f32: 128x32 f32 = 1024 chunks16B
      const int c = i * 256 + t;
      const int row = c >> 3, cc = c & 7;        // 8 chunks (4 f32) per row
      const int gc = cc ^ (row & 7);             // source-side swizzle
      const int cbase = i * 256 + w * 64;        // wave-uniform
      gload16(&B[(size_t)(nBase + row) * ldb + k0 + gc * 4], &Bs[buf][cbase * 4]);
    }
  };

  const int nsteps = K >> 5;
  stage(0, 0);
  if (nsteps > 1) stage(1, 32);
  for (int ts = 0; ts < nsteps; ++ts) {
    const int cur = ts & 1;
    if (ts + 1 < nsteps) { asm volatile("s_waitcnt vmcnt(8)" ::: "memory"); }
    else                 { asm volatile("s_waitcnt vmcnt(0)" ::: "memory"); }
    __builtin_amdgcn_s_barrier();
    FENCE();
    h16x8 aH[4], bH[4], aL[4], bL[4];
#pragma unroll
    for (int mi = 0; mi < 4; mi++) {
      const int r = wr + mi * 16 + r16;
      const int off = r * 32 + (kq ^ ((r >> 1) & 3)) * 8;
      aH[mi] = *(const h16x8*)&As[cur][off];
      aL[mi] = *(const h16x8*)&As[cur][4096 + off];
    }
#pragma unroll
    for (int ni = 0; ni < 4; ni++) {
      const int r = wc + ni * 16 + r16;
      const int swz = r & 7;
      f32x4 v0 = *(const f32x4*)&Bs[cur][r * 32 + ((2 * kq) ^ swz) * 4];
      f32x4 v1 = *(const f32x4*)&Bs[cur][r * 32 + ((2 * kq + 1) ^ swz) * 4];
#pragma unroll
      for (int j = 0; j < 4; j++) {
        _Float16 h0 = (_Float16)v0[j];
        _Float16 h1 = (_Float16)v1[j];
        bH[ni][j] = h0;       bH[ni][j + 4] = h1;
        bL[ni][j] = (_Float16)(v0[j] - (float)h0);
        bL[ni][j + 4] = (_Float16)(v1[j] - (float)h1);
      }
    }
    __builtin_amdgcn_s_setprio(1);
#pragma unroll
    for (int mi = 0; mi < 4; mi++)
#pragma unroll
      for (int ni = 0; ni < 4; ni++) {
        acc[mi][ni] = __builtin_amdgcn_mfma_f32_16x16x32_f16(aH[mi], bH[ni], acc[mi][ni], 0, 0, 0);
        acc[mi][ni] = __builtin_amdgcn_mfma_f32_16x16x32_f16(aH[mi], bL[ni], acc[mi][ni], 0, 0, 0);
        acc[mi][ni] = __builtin_amdgcn_mfma_f32_16x16x32_f16(aL[mi], bH[ni], acc[mi][ni], 0, 0, 0);
      }
    __builtin_amdgcn_s_setprio(0);
    FENCE();
    __builtin_amdgcn_s_barrier();
    FENCE();
    if (ts + 2 < nsteps) stage(cur, (ts + 2) * 32);
  }
  FENCE();

  unsigned short* C16 = Cout + (size_t)z * sC;
  unsigned short* C16b = Cout2 + (size_t)z * sC;
  const float* mu1b = mu1 + (size_t)z * 8192;
  short* ep = &As[0][0] + w * 4096;   // 8 KB per wave in dead As
  unsigned pk[4][4][4];
#pragma unroll
  for (int mi = 0; mi < 4; mi++)
#pragma unroll
    for (int ni = 0; ni < 4; ni++) {
      const int cl = nBase + wc + ni * 16 + r16;
      const float muc = mu1b[cl * 2];
      const float isc = mu1b[cl * 2 + 1];
#pragma unroll
      for (int r = 0; r < 4; r++) {
        const int rw = mBase + wr + mi * 16 + kq * 4 + r;
        float v = isc * (acc[mi][ni][r] - muc * Svec[rw]) + B0vec[rw];
        pk[mi][ni][r] = split16(v);
      }
    }
#pragma unroll
  for (int mi = 0; mi < 4; mi++)
#pragma unroll
    for (int ni = 0; ni < 4; ni++)
#pragma unroll
      for (int r = 0; r < 4; r++)
        ep[(mi * 16 + kq * 4 + r) * 64 + ni * 16 + r16] =
            (short)(pk[mi][ni][r] & 0xffffu);
#pragma unroll
  for (int j = 0; j < 8; j++) {
    const int f = j * 512 + l * 8;
    const int row = f >> 6, col = f & 63;
    *(u16x8*)&C16[(size_t)(mBase + wr + row) * ldc + nBase + wc + col] =
        *(const u16x8*)&ep[f];
  }
#pragma unroll
  for (int mi = 0; mi < 4; mi++)
#pragma unroll
    for (int ni = 0; ni < 4; ni++)
#pragma unroll
      for (int r = 0; r < 4; r++)
        ep[(mi * 16 + kq * 4 + r) * 64 + ni * 16 + r16] =
            (short)(pk[mi][ni][r] >> 16);
#pragma unroll
  for (int j = 0; j < 8; j++) {
    const int f = j * 512 + l * 8;
    const int row = f >> 6, col = f & 63;
    *(u16x8*)&C16b[(size_t)(mBase + wr + row) * ldc + nBase + wc + col] =
        *(const u16x8*)&ep[f];
  }
}

// ================= split-path GEMM: C = A(MxK) * B(NxK)^T ==================
// fp16-split hi/lo, 128x128 tile, BK=32, 4 waves (2x2), dbuf LDS (64 KB),
// counted vmcnt(8).
// EPI: 5 f32 out | 6 f16 hi/lo +bias[row] +gelu | 7 f32 +bias[row]
template <int EPI>
__global__ __launch_bounds__(256)
void gemm_s(const unsigned short* __restrict__ Ahi, const unsigned short* __restrict__ Alo,
            const unsigned short* __restrict__ Bhi, const unsigned short* __restrict__ Blo,
            void* __restrict__ Cout, unsigned short* __restrict__ Cout2,
            const float* __restrict__ bias,
            int K, int lda, int ldb, int ldc,
            long long sA, long long sB, long long sC, int splitK) {
  __shared__ short As[2][8192];   // [buf][plane(hi 0 / lo 4096)][128x32]
  __shared__ short Bs[2][8192];
  const int z = blockIdx.z;
  const int bi = z / splitK, sp = z % splitK;
  const int kLen = K / splitK, kStart = sp * kLen;
  const unsigned short* AH = Ahi + (size_t)bi * sA;
  const unsigned short* BH = Bhi + (size_t)bi * sB;
  const unsigned short* AL = Alo + (size_t)bi * sA;
  const unsigned short* BL = Blo + (size_t)bi * sB;
  int bx = blockIdx.x, by = blockIdx.y;
  xcd_swz(bx, by, gridDim.x, gridDim.y);
  const int mBase = by * 128, nBase = bx * 128;
  const int t = threadIdx.x, w = t >> 6, l = t & 63;
  const int r16 = l & 15, kq = l >> 4;
  const int wr = (w >> 1) * 64, wc = (w & 1) * 64;
  f32x4 acc[4][4] = {};

  auto stage = [&](int buf, int k0) {   // 8 vector-mem instrs per wave
#pragma unroll
    for (int i = 0; i < 2; ++i) {
      const int c = i * 256 + t;
      const int row = c >> 2, cc = c & 3;
      const int gc = cc ^ ((row >> 1) & 3);
      const int cbase = i * 256 + w * 64;
      const size_t ga = (size_t)(mBase + row) * lda + k0 + gc * 8;
      const size_t gb = (size_t)(nBase + row) * ldb + k0 + gc * 8;
      gload16(&AH[ga], &As[buf][cbase * 8]);
      gload16(&AL[ga], &As[buf][4096 + cbase * 8]);
      gload16(&BH[gb], &Bs[buf][cbase * 8]);
      gload16(&BL[gb], &Bs[buf][4096 + cbase * 8]);
    }
  };

  const int nsteps = kLen >> 5;
  stage(0, kStart);
  if (nsteps > 1) stage(1, kStart + 32);
  for (int ts = 0; ts < nsteps; ++ts) {
    const int cur = ts & 1;
    if (ts + 1 < nsteps) { asm volatile("s_waitcnt vmcnt(8)" ::: "memory"); }
    else                 { asm volatile("s_waitcnt vmcnt(0)" ::: "memory"); }
    __builtin_amdgcn_s_barrier();
    FENCE();
    h16x8 aH[4], bH[4], aL[4], bL[4];
#pragma unroll
    for (int mi = 0; mi < 4; mi++) {
      const int r = wr + mi * 16 + r16;
      const int off = r * 32 + (kq ^ ((r >> 1) & 3)) * 8;
      aH[mi] = *(const h16x8*)&As[cur][off];
      aL[mi] = *(const h16x8*)&As[cur][4096 + off];
    }
#pragma unroll
    for (int ni = 0; ni < 4; ni++) {
      const int r = wc + ni * 16 + r16;
      const int off = r * 32 + (kq ^ ((r >> 1) & 3)) * 8;
      bH[ni] = *(const h16x8*)&Bs[cur][off];
      bL[ni] = *(const h16x8*)&Bs[cur][4096 + off];
    }
    __builtin_amdgcn_s_setprio(1);
#pragma unroll
    for (int mi = 0; mi < 4; mi++)
#pragma unroll
      for (int ni = 0; ni < 4; ni++) {
        acc[mi][ni] = __builtin_amdgcn_mfma_f32_16x16x32_f16(aH[mi], bH[ni], acc[mi][ni], 0, 0, 0);
        acc[mi][ni] = __builtin_amdgcn_mfma_f32_16x16x32_f16(aH[mi], bL[ni], acc[mi][ni], 0, 0, 0);
        acc[mi][ni] = __builtin_amdgcn_mfma_f32_16x16x32_f16(aL[mi], bH[ni], acc[mi][ni], 0, 0, 0);
      }
    __builtin_amdgcn_s_setprio(0);
    FENCE();
    __builtin_amdgcn_s_barrier();
    FENCE();
    if (ts + 2 < nsteps) stage(cur, kStart + (ts + 2) * 32);
  }
  FENCE();

  unsigned short* C16 = (unsigned short*)Cout + (size_t)z * sC;
  unsigned short* C16b = Cout2 ? Cout2 + (size_t)z * sC : nullptr;
  float* C32 = (float*)Cout + (size_t)z * sC;

  if constexpr (EPI == 6) {
    short* ep = &As[0][0] + w * 4096;   // 8 KB per wave in dead As
    unsigned pk[4][4][4];
#pragma unroll
    for (int mi = 0; mi < 4; mi++)
#pragma unroll
      for (int ni = 0; ni < 4; ni++)
#pragma unroll
        for (int r = 0; r < 4; r++) {
          float v = acc[mi][ni][r] + bias[mBase + wr + mi * 16 + kq * 4 + r];
          pk[mi][ni][r] = split16(gelu_f(v));
        }
#pragma unroll
    for (int mi = 0; mi < 4; mi++)
#pragma unroll
      for (int ni = 0; ni < 4; ni++)
#pragma unroll
        for (int r = 0; r < 4; r++)
          ep[(mi * 16 + kq * 4 + r) * 64 + ni * 16 + r16] =
              (short)(pk[mi][ni][r] & 0xffffu);
#pragma unroll
    for (int j = 0; j < 8; j++) {
      const int f = j * 512 + l * 8;
      const int row = f >> 6, col = f & 63;
      *(u16x8*)&C16[(size_t)(mBase + wr + row) * ldc + nBase + wc + col] =
          *(const u16x8*)&ep[f];
    }
#pragma unroll
    for (int mi = 0; mi < 4; mi++)
#pragma unroll
      for (int ni = 0; ni < 4; ni++)
#pragma unroll
        for (int r = 0; r < 4; r++)
          ep[(mi * 16 + kq * 4 + r) * 64 + ni * 16 + r16] =
              (short)(pk[mi][ni][r] >> 16);
#pragma unroll
    for (int j = 0; j < 8; j++) {
      const int f = j * 512 + l * 8;
      const int row = f >> 6, col = f & 63;
      *(u16x8*)&C16b[(size_t)(mBase + wr + row) * ldc + nBase + wc + col] =
          *(const u16x8*)&ep[f];
    }
  } else {
#pragma unroll
    for (int mi = 0; mi < 4; mi++) {
#pragma unroll
      for (int ni = 0; ni < 4; ni++) {
        const int cl = nBase + wc + ni * 16 + r16;
#pragma unroll
        for (int r = 0; r < 4; r++) {
          const int rw = mBase + wr + mi * 16 + kq * 4 + r;
          float v = acc[mi][ni][r];
          if (EPI == 7) v += bias[rw];
          C32[(size_t)rw * ldc + cl] = v;
        }
      }
    }
  }
}

// ---------------- energy split-K reduce -> f16 hi/lo -----------------------
__global__ __launch_bounds__(256)
void ereduce_kernel(const float* __restrict__ part, unsigned short* __restrict__ ehi,
                    unsigned short* __restrict__ elo) {
  const size_t idx = (size_t)blockIdx.x * 256 + threadIdx.x;  // 8*65536 total
  const size_t b = idx >> 16, i = idx & 65535;
  const float* p = part + b * (8ull * 65536) + i;
  float s0 = (p[0] + p[65536]) + (p[2 * 65536] + p[3 * 65536]);
  float s1 = (p[4 * 65536] + p[5 * 65536]) + (p[6 * 65536] + p[7 * 65536]);
  unsigned pk = split16(s0 + s1);
  ehi[idx] = (unsigned short)(pk & 0xffffu);
  elo[idx] = (unsigned short)(pk >> 16);
}

// ---------------- softmax over rows + transpose -> f16 ---------------------
__global__ __launch_bounds__(256)
void smax_t_kernel(const float* __restrict__ a2, unsigned short* __restrict__ attT) {
  __shared__ float S[8][1028];
  __shared__ float inv[8];
  const int t = threadIdx.x;
  const int b = blockIdx.y;
  const int o0 = blockIdx.x * 8;
  const float* src = a2 + ((size_t)b * 1024 + o0) * 1024;
#pragma unroll
  for (int i = 0; i < 8; i++)
    *(f32x4*)&S[i][t * 4] = *(const f32x4*)&src[(size_t)i * 1024 + t * 4];
  __syncthreads();
  const int w = t >> 6, l = t & 63;
  for (int rr = 0; rr < 2; rr++) {
    const int r = w * 2 + rr;
    float m = -1e30f;
#pragma unroll
    for (int i = 0; i < 16; i++) m = fmaxf(m, S[r][l + i * 64]);
#pragma unroll
    for (int o = 32; o > 0; o >>= 1) m = fmaxf(m, __shfl_xor(m, o));
    float ssum = 0.0f;
#pragma unroll
    for (int i = 0; i < 16; i++) {
      float e = expf(S[r][l + i * 64] - m);
      S[r][l + i * 64] = e;
      ssum += e;
    }
#pragma unroll
    for (int o = 32; o > 0; o >>= 1) ssum += __shfl_xor(ssum, o);
    if (l == 0) inv[r] = 1.0f / ssum;
  }
  __syncthreads();
  float iv[8];
#pragma unroll
  for (int r = 0; r < 8; r++) iv[r] = inv[r];
#pragma unroll
  for (int i = 0; i < 4; i++) {
    const int k = i * 256 + t;
    u16x8 ov;
#pragma unroll
    for (int r = 0; r < 8; r++) ov[r] = f2h(S[r][k] * iv[r]);
    *(u16x8*)&attT[((size_t)b * 1024 + k) * 1024 + o0] = ov;
  }
}

// ---------------------------------------------------------------------------
extern "C" void kernel_launch(void* const* d_in, const int* in_sizes, int n_in,
                              void* d_out, int out_size, void* d_ws, size_t ws_size,
                              hipStream_t stream) {
  (void)in_sizes; (void)n_in; (void)out_size; (void)ws_size;
  const float* x     = (const float*)d_in[1];
  const float* ln1_g = (const float*)d_in[2];
  const float* ln1_b = (const float*)d_in[3];
  const float* ln2_g = (const float*)d_in[4];
  const float* ln2_b = (const float*)d_in[5];
  const float* qk_w  = (const float*)d_in[6];
  const float* v_w   = (const float*)d_in[7];
  const float* v_b   = (const float*)d_in[8];
  const float* t1_w  = (const float*)d_in[9];
  const float* t1_b  = (const float*)d_in[10];
  const float* t2_w  = (const float*)d_in[11];
  const float* t2_b  = (const float*)d_in[12];
  const float* m1_w  = (const float*)d_in[13];
  const float* m1_b  = (const float*)d_in[14];
  const float* m2_w  = (const float*)d_in[15];
  const float* m2_b  = (const float*)d_in[16];

  char* ws = (char*)d_ws;
  unsigned short* xhi  = (unsigned short*)(ws + 0);            // 67 MB
  unsigned short* gb   = (unsigned short*)(ws + 67108864);     // 67 MB (scratch)
  unsigned short* Qthi = (unsigned short*)(ws + 134217728);    // 16.8 MB
  unsigned short* Qtlo = (unsigned short*)(ws + 150994944);    // 16.8 MB
  float*          part = (float*)(ws + 167772160);             // 16.8 MB
  unsigned short* Ehi  = (unsigned short*)(ws + 184549376);    // 1 MB
  unsigned short* Elo  = (unsigned short*)(ws + 185597952);    // 1 MB
  unsigned short* Ghi  = (unsigned short*)(ws + 186646528);    // 4.2 MB
  unsigned short* Glo  = (unsigned short*)(ws + 190840832);    // 4.2 MB
  float*          a2   = (float*)(ws + 195035136);             // 33.5 MB
  unsigned short* attT = (unsigned short*)(ws + 228589568);    // 16.8 MB
  unsigned short* WeT  = (unsigned short*)(ws + 245366784);    // 16.8 MB
  float*          add1 = (float*)(ws + 262144000);             // 32 KB
  float*          Sg   = (float*)(ws + 262176768);             // 32 KB
  float*          muis1= (float*)(ws + 262209536);             // 256 KB
  float*          muis2= (float*)(ws + 262471680);             // 256 KB
  float*          SvM1 = (float*)(ws + 262733824);             // 4 KB
  float*          b2   = (float*)(ws + 262737920);             // 4 KB
  float*          SQt  = (float*)(ws + 262742016);             // 1 KB
  float*          B0Qt = (float*)(ws + 262746112);             // 1 KB
  float*          gv   = (float*)(ws + 262750208);             // 4 KB
  float*          vb2  = (float*)(ws + 262754304);             // 4 KB
  unsigned short* x1h  = (unsigned short*)(ws + 335544320);    // 67 MB
  unsigned short* wqh  = (unsigned short*)(ws + 446693376);    // 0.5 MB
  unsigned short* wql  = (unsigned short*)(ws + 447217664);
  unsigned short* wvt  = (unsigned short*)(ws + 447741952);    // 2 MB (g-folded T)
  unsigned short* wt1h = (unsigned short*)(ws + 449839104);
  unsigned short* wt1l = (unsigned short*)(ws + 450363392);
  unsigned short* wt2h = (unsigned short*)(ws + 450887680);
  unsigned short* wt2l = (unsigned short*)(ws + 451411968);
  unsigned short* wm1p = (unsigned short*)(ws + 451936256);    // 2 MB (m1_w * g)
  unsigned short* wm2  = (unsigned short*)(ws + 454033408);    // 2 MB
  float* out = (float*)d_out;

  // weight converts / prep (LN1 folded into wq', wvt, gv/vb2)
  wqprep_kernel<<<dim3(256), dim3(256), 0, stream>>>(qk_w, ln1_g, ln1_b, wqh, wql, SQt, B0Qt);
  vwt_kernel<<<dim3(16, 16), dim3(256), 0, stream>>>(v_w, ln1_g, wvt);
  vwvec_kernel<<<dim3(1024), dim3(256), 0, stream>>>(v_w, ln1_g, ln1_b, v_b, gv, vb2);
  cvt_kernel<<<dim3(256),  dim3(256), 0, stream>>>(t1_w, wt1h, wt1l, 65536);
  cvt_kernel<<<dim3(256),  dim3(256), 0, stream>>>(t2_w, wt2h, wt2l, 65536);
  m1prep_kernel<<<dim3(1024), dim3(256), 0, stream>>>(m1_w, ln2_g, ln2_b, m1_b, wm1p, SvM1, b2);
  cvt_kernel<<<dim3(1024), dim3(256), 0, stream>>>(m2_w, wm2, nullptr, 262144);
  // x -> f16 hi plane + LN1 stats (xlo deleted: Qt splits from raw f32)
  lnsplit_kernel<<<dim3(32768), dim3(256), 0, stream>>>(x, xhi, muis1);
  // Qt[b](256x4096) = (qk_w.g) @ x[b]^T, LN1-corrected epilogue (SWAP grid)
  gemm_q<<<dim3(2, 32, 8), dim3(256), 0, stream>>>(
      wqh, wql, x, Qthi, Qtlo, SQt, B0Qt, muis1,
      1024, 1024, 1024, 4096, 4194304, 1048576);
  // energy partials: part[b*8+s](256x256) = Qt[b] @ Qt[b]^T over k-chunk s
  gemm_s<5><<<dim3(2, 2, 64), dim3(256), 0, stream>>>(
      Qthi, Qtlo, Qthi, Qtlo, part, nullptr, nullptr,
      4096, 4096, 4096, 256, 1048576, 1048576, 65536, 8);
  ereduce_kernel<<<dim3(2048), dim3(256), 0, stream>>>(part, Ehi, Elo);
  // G[b](1024x256) = gelu(t1_w @ en[b] + t1_b)  (en symmetric -> NT; split out)
  gemm_s<6><<<dim3(2, 8, 8), dim3(256), 0, stream>>>(
      wt1h, wt1l, Ehi, Elo, Ghi, Glo, t1_b,
      256, 256, 256, 256, 0, 65536, 262144, 1);
  // a2[b](1024x1024) = t2_w @ G[b]^T + t2_b  (f32 out)
  gemm_s<7><<<dim3(8, 8, 8), dim3(256), 0, stream>>>(
      wt2h, wt2l, Ghi, Glo, a2, nullptr, t2_b,
      256, 256, 256, 1024, 0, 262144, 1048576, 1);
  // attT[b] = softmax(a2[b], -1)^T  (f16)
  smax_t_kernel<<<dim3(128, 8), dim3(256), 0, stream>>>(a2, attT);
  // WeT'[b](1024x1024) = attT[b] @ wvt^T  (g-folded, f16)
  gemm_v<4><<<dim3(8, 8, 8), dim3(256), 0, stream>>>(
      attT, wvt, WeT, nullptr, nullptr, nullptr, nullptr,
      1024, 1024, 1024, 1024, 1048576, 0, 1048576, 0, 0);
  // add1[b][q] = attT_row @ (v_b + v_w@b);  Sg[b][q] = attT_row @ (v_w@g)
  attdots_kernel<<<dim3(256, 8), dim3(256), 0, stream>>>(attT, vb2, gv, add1, Sg);
  // x1[b](4096x1024, f16) = is*(x@WeT' - mu*Sg) + add1 + x   (res = xhi)
  gemm_r<<<dim3(8, 32, 8), dim3(256), 0, stream>>>(
      xhi, WeT, x1h, muis1, Sg, add1, xhi,
      1024, 1024, 1024, 1024, 4194304, 1048576, 4194304, 4194304);
  // LN2 stats from x1h
  stats16_kernel<<<dim3(32768), dim3(256), 0, stream>>>(x1h, muis2);
  // g = gelu(is*(x1h @ wm1p^T - mu*S) + b2)   (LN2 folded into epilogue)
  gemm_v<9><<<dim3(8, 256, 1), dim3(256), 0, stream>>>(
      x1h, wm1p, gb, b2, nullptr, muis2, SvM1,
      1024, 1024, 1024, 1024, 0, 0, 0, 0, 0);
  // out = x1 + g @ m2_w^T + m2_b (f32; res = f16 x1)
  gemm_v<3><<<dim3(8, 256, 1), dim3(256), 0, stream>>>(
      gb, wm2, out, m2_b, x1h, nullptr, nullptr,
      1024, 1024, 1024, 1024, 0, 0, 0, 0, 0);
}